// Round 3
// baseline (1860.054 us; speedup 1.0000x reference)
//
#include <hip/hip_runtime.h>
#include <cstdint>

typedef __bf16 bf16;
typedef __bf16 bf16x8 __attribute__((ext_vector_type(8)));
typedef float  f32x4  __attribute__((ext_vector_type(4)));

// ---------------- fp32 -> bf16 cast (n multiple of 2048) ----------------
__global__ __launch_bounds__(256) void f2b_kernel(const float* __restrict__ in, bf16* __restrict__ out) {
  long i = ((long)blockIdx.x * 256 + threadIdx.x) * 8;
  float4 a = *(const float4*)(in + i);
  float4 b = *(const float4*)(in + i + 4);
  bf16 o[8] = {(bf16)a.x, (bf16)a.y, (bf16)a.z, (bf16)a.w,
               (bf16)b.x, (bf16)b.y, (bf16)b.z, (bf16)b.w};
  *(uint4*)(out + i) = *(uint4*)o;
}

// ---------------- LayerNorm (fp32 in, bf16 out): one wave per row of 512 ----------------
__global__ __launch_bounds__(64) void ln_kernel(const float* __restrict__ x,
    const float* __restrict__ w, const float* __restrict__ b, bf16* __restrict__ xn) {
  long row = blockIdx.x;
  int t = threadIdx.x;
  const float* rp = x + row * 512 + t * 8;
  float4 p0 = *(const float4*)rp;
  float4 p1 = *(const float4*)(rp + 4);
  float vals[8] = {p0.x, p0.y, p0.z, p0.w, p1.x, p1.y, p1.z, p1.w};
  float s = 0.f, s2 = 0.f;
#pragma unroll
  for (int e = 0; e < 8; e++) { s += vals[e]; s2 += vals[e] * vals[e]; }
#pragma unroll
  for (int o = 32; o > 0; o >>= 1) { s += __shfl_xor(s, o); s2 += __shfl_xor(s2, o); }
  float mu = s * (1.f / 512.f);
  float var = s2 * (1.f / 512.f) - mu * mu;
  float rstd = rsqrtf(var + 1e-5f);
  float4 w0 = *(const float4*)(w + t * 8), w1 = *(const float4*)(w + t * 8 + 4);
  float4 b0 = *(const float4*)(b + t * 8), b1 = *(const float4*)(b + t * 8 + 4);
  float wv[8] = {w0.x, w0.y, w0.z, w0.w, w1.x, w1.y, w1.z, w1.w};
  float bv[8] = {b0.x, b0.y, b0.z, b0.w, b1.x, b1.y, b1.z, b1.w};
  bf16 outv[8];
#pragma unroll
  for (int e = 0; e < 8; e++) outv[e] = (bf16)((vals[e] - mu) * rstd * wv[e] + bv[e]);
  *(uint4*)(xn + row * 512 + t * 8) = *(uint4*)outv;
}

// ---------------- batched MFMA GEMM ----------------
// C[M,N] = alpha * A[M,K] @ op(B),  A,B bf16 row-major.
// BT=true : B stored [N,K] (C = A @ B^T);  BT=false: B stored [K,N].
enum { MODE_BF16 = 1, MODE_QKV = 2, MODE_RESID = 3 };

template <int BM, int BN, bool BT, int MODE>
__global__ __launch_bounds__(256) void gemm_k(
    const bf16* __restrict__ A, const bf16* __restrict__ B, void* __restrict__ C,
    int M, int N, int K, long sA, long sB, long sC, float alpha,
    const float* __restrict__ resid, const float* __restrict__ bias,
    bf16* __restrict__ q_out, bf16* __restrict__ k_out, bf16* __restrict__ v_out) {
  constexpr int BK = 32, LDST = 40;  // 80B row stride: 16B-aligned, non-pow2
  __shared__ __align__(16) bf16 As[BM * LDST];
  __shared__ __align__(16) bf16 Bs[BN * LDST];
  const int tid = threadIdx.x, lane = tid & 63, wave = tid >> 6;
  const int quad = lane >> 4, l16 = lane & 15;
  constexpr int WN = (BN >= 128) ? 2 : 1;
  constexpr int WM = 4 / WN;
  constexpr int TM = BM / (WM * 16), TN = BN / (WN * 16);
  const int wm0 = (wave / WN) * (BM / WM);
  const int wn0 = (wave % WN) * (BN / WN);
  const int bm0 = blockIdx.x * BM, bn0 = blockIdx.y * BN;
  const bf16* Ab = A + (long)blockIdx.z * sA;
  const bf16* Bb = B + (long)blockIdx.z * sB;

  f32x4 zero = {0.f, 0.f, 0.f, 0.f};
  f32x4 acc[TM][TN];
#pragma unroll
  for (int i = 0; i < TM; i++)
#pragma unroll
    for (int j = 0; j < TN; j++) acc[i][j] = zero;

  for (int k0 = 0; k0 < K; k0 += BK) {
    for (int c = tid; c < BM * 4; c += 256) {
      int r = c >> 2, cv = (c & 3) * 8;
      *(uint4*)&As[r * LDST + cv] = *(const uint4*)&Ab[(long)(bm0 + r) * K + k0 + cv];
    }
    if (BT) {
      for (int c = tid; c < BN * 4; c += 256) {
        int r = c >> 2, cv = (c & 3) * 8;
        *(uint4*)&Bs[r * LDST + cv] = *(const uint4*)&Bb[(long)(bn0 + r) * K + k0 + cv];
      }
    } else {
      for (int c = tid; c < BN * 4; c += 256) {
        int kk = c / (BN / 8), nv = (c % (BN / 8)) * 8;
        uint4 tmp = *(const uint4*)&Bb[(long)(k0 + kk) * N + bn0 + nv];
        const bf16* tv = (const bf16*)&tmp;
#pragma unroll
        for (int e = 0; e < 8; e++) Bs[(nv + e) * LDST + kk] = tv[e];
      }
    }
    __syncthreads();
    bf16x8 af[TM], bfr[TN];
#pragma unroll
    for (int i = 0; i < TM; i++)
      af[i] = *(const bf16x8*)&As[(wm0 + i * 16 + l16) * LDST + quad * 8];
#pragma unroll
    for (int j = 0; j < TN; j++)
      bfr[j] = *(const bf16x8*)&Bs[(wn0 + j * 16 + l16) * LDST + quad * 8];
#pragma unroll
    for (int i = 0; i < TM; i++)
#pragma unroll
      for (int j = 0; j < TN; j++)
        acc[i][j] = __builtin_amdgcn_mfma_f32_16x16x32_bf16(af[i], bfr[j], acc[i][j], 0, 0, 0);
    __syncthreads();
  }

  const long cb = (long)blockIdx.z * sC;
#pragma unroll
  for (int i = 0; i < TM; i++)
#pragma unroll
    for (int j = 0; j < TN; j++)
#pragma unroll
      for (int r = 0; r < 4; r++) {
        int row = bm0 + wm0 + i * 16 + quad * 4 + r;   // C/D: row = quad*4+reg
        int col = bn0 + wn0 + j * 16 + l16;            //      col = lane&15
        float v = acc[i][j][r] * alpha;
        if (MODE == MODE_BF16) {
          ((bf16*)C)[cb + (long)row * N + col] = (bf16)v;
        } else if (MODE == MODE_QKV) {
          int b = row >> 12, n = row & 4095;
          int which = col >> 9, h = (col >> 6) & 7, d = col & 63;
          long o = ((long)(b * 8 + h) * 4096 + n) * 64 + d;
          if (which == 0) q_out[o] = (bf16)(v * 0.125f);  // q * DH^-0.5
          else if (which == 1) k_out[o] = (bf16)v;
          else v_out[o] = (bf16)v;
        } else {  // MODE_RESID: fp32 out = acc + bias + x
          long o = (long)row * N + col;
          ((float*)C)[o] = v + bias[col] + resid[o];
        }
      }
}

// ---------------- landmark means (16 tokens per landmark) ----------------
__global__ __launch_bounds__(64) void lm_kernel(const bf16* __restrict__ q, const bf16* __restrict__ k,
                                                bf16* __restrict__ ql, bf16* __restrict__ kl) {
  int bh = blockIdx.x, mi = blockIdx.y, d = threadIdx.x;
  long base = ((long)bh * 4096 + mi * 16) * 64 + d;
  float sq = 0.f, sk = 0.f;
#pragma unroll
  for (int j = 0; j < 16; j++) { sq += (float)q[base + j * 64]; sk += (float)k[base + j * 64]; }
  long o = ((long)bh * 256 + mi) * 64 + d;
  ql[o] = (bf16)(sq * (1.f / 16.f));
  kl[o] = (bf16)(sk * (1.f / 16.f));
}

// ---------------- in-place softmax over 256 cols ----------------
__global__ __launch_bounds__(256) void softmax256(bf16* __restrict__ buf) {
  long row = blockIdx.x;
  int t = threadIdx.x, lane = t & 63, wave = t >> 6;
  __shared__ float sm[4];
  float v = (float)buf[row * 256 + t];
  float m = v;
#pragma unroll
  for (int o = 32; o > 0; o >>= 1) m = fmaxf(m, __shfl_xor(m, o));
  if (lane == 0) sm[wave] = m;
  __syncthreads();
  m = fmaxf(fmaxf(sm[0], sm[1]), fmaxf(sm[2], sm[3]));
  float e = __expf(v - m);
  __syncthreads();
  float s = e;
#pragma unroll
  for (int o = 32; o > 0; o >>= 1) s += __shfl_xor(s, o);
  if (lane == 0) sm[wave] = s;
  __syncthreads();
  s = sm[0] + sm[1] + sm[2] + sm[3];
  buf[row * 256 + t] = (bf16)(e / s);
}

// ---------------- in-place softmax over 4096 cols ----------------
__global__ __launch_bounds__(256) void softmax4096(bf16* __restrict__ buf) {
  long row = blockIdx.x;
  int t = threadIdx.x, lane = t & 63, wave = t >> 6;
  __shared__ float sm[4];
  bf16* rp = buf + row * 4096;
  float vals[16];
  float m = -3.4e38f;
#pragma unroll
  for (int i = 0; i < 16; i++) { vals[i] = (float)rp[t + i * 256]; m = fmaxf(m, vals[i]); }
#pragma unroll
  for (int o = 32; o > 0; o >>= 1) m = fmaxf(m, __shfl_xor(m, o));
  if (lane == 0) sm[wave] = m;
  __syncthreads();
  m = fmaxf(fmaxf(sm[0], sm[1]), fmaxf(sm[2], sm[3]));
  float s = 0.f;
#pragma unroll
  for (int i = 0; i < 16; i++) { vals[i] = __expf(vals[i] - m); s += vals[i]; }
  __syncthreads();
#pragma unroll
  for (int o = 32; o > 0; o >>= 1) s += __shfl_xor(s, o);
  if (lane == 0) sm[wave] = s;
  __syncthreads();
  s = sm[0] + sm[1] + sm[2] + sm[3];
  float inv = 1.f / s;
#pragma unroll
  for (int i = 0; i < 16; i++) rp[t + i * 256] = (bf16)(vals[i] * inv);
}

// ---------------- pinv helpers ----------------
__global__ void init_scal(float* scal) { ((int*)scal)[0] = 0; ((int*)scal)[1] = 0; }

__global__ __launch_bounds__(64) void red_row(const bf16* __restrict__ a2h, float* scal) {
  long row = blockIdx.x;
  int t = threadIdx.x;
  float s = 0.f;
#pragma unroll
  for (int c = 0; c < 4; c++) s += (float)a2h[row * 256 + t + 64 * c];
#pragma unroll
  for (int o = 32; o > 0; o >>= 1) s += __shfl_xor(s, o);
  if (t == 0) atomicMax((int*)scal, __float_as_int(s));
}

__global__ __launch_bounds__(64) void red_col(const bf16* __restrict__ a2h, float* scal) {
  int bh = blockIdx.x;
  int j = blockIdx.y * 64 + threadIdx.x;
  float s = 0.f;
  const bf16* p = a2h + (long)bh * 65536 + j;
  for (int i = 0; i < 256; i++) s += (float)p[i * 256];
  atomicMax((int*)scal + 1, __float_as_int(s));
}

__global__ __launch_bounds__(256) void z0_k(const bf16* __restrict__ a2h,
                                            const float* __restrict__ scal, bf16* __restrict__ z) {
  int bh = blockIdx.x, i = blockIdx.y, j = threadIdx.x;
  float inv = 1.f / (scal[0] * scal[1]);
  float v = (float)a2h[((long)bh * 256 + i) * 256 + j];
  z[((long)bh * 256 + j) * 256 + i] = (bf16)(v * inv);
}

// out = bf16(cdiag*I - in)
__global__ __launch_bounds__(256) void ew_diag(float cdiag, const bf16* __restrict__ in,
                                               bf16* __restrict__ outh) {
  int bh = blockIdx.x, i = blockIdx.y, j = threadIdx.x;
  long idx = ((long)bh * 256 + i) * 256 + j;
  outh[idx] = (bf16)(((i == j) ? cdiag : 0.f) - (float)in[idx]);
}

// ---------------- depthwise conv residual + reorder to [b,n,h*d] ----------------
__global__ __launch_bounds__(256) void conv_combine(const bf16* __restrict__ attn,
    const bf16* __restrict__ v, const float* __restrict__ wconv, bf16* __restrict__ xattn) {
  int bh = blockIdx.x, nb = blockIdx.y;  // 64 tokens per block
  int h = bh & 7, b = bh >> 3;
  __shared__ __align__(16) bf16 vs[96][64];
  __shared__ float wcf[33];
  int t = threadIdx.x;
  long vbase = (long)bh * 4096 * 64;
  for (int c = t; c < 768; c += 256) {
    int r = c >> 3, c8 = (c & 7) * 8;
    int n = nb * 64 - 16 + r;
    uint4 val = {0u, 0u, 0u, 0u};
    if (n >= 0 && n < 4096) val = *(const uint4*)&v[vbase + (long)n * 64 + c8];
    *(uint4*)&vs[r][c8] = val;
  }
  if (t < 33) wcf[t] = wconv[h * 33 + t];
  __syncthreads();
  int d = t & 63;
  for (int nl = t >> 6; nl < 64; nl += 4) {
    int n = nb * 64 + nl;
    float acc = (float)attn[vbase + (long)n * 64 + d];
#pragma unroll
    for (int kk = 0; kk < 33; kk++) acc += (float)vs[nl + kk][d] * wcf[kk];
    xattn[(((long)b * 4096 + n) << 9) + (h << 6) + d] = (bf16)acc;
  }
}

// ---------------- host ----------------
extern "C" void kernel_launch(void* const* d_in, const int* in_sizes, int n_in,
                              void* d_out, int out_size, void* d_ws, size_t ws_size,
                              hipStream_t stream) {
  (void)in_sizes; (void)n_in; (void)out_size; (void)ws_size;
  const float* x      = (const float*)d_in[0];   // fp32 per reference dtypes
  const float* ln_w   = (const float*)d_in[1];
  const float* ln_b   = (const float*)d_in[2];
  const float* w_qkv  = (const float*)d_in[3];
  const float* w_out  = (const float*)d_in[4];
  const float* b_out  = (const float*)d_in[5];
  const float* w_conv = (const float*)d_in[6];
  float* out = (float*)d_out;                    // fp32 output

  // ---- workspace plan (~94.5 MB, overlays with disjoint lifetimes) ----
  char* ws = (char*)d_ws;
  const size_t MB = 1u << 20;
  bf16* q      = (bf16*)(ws + 0 * MB);    // [32,4096,64] live: qkv..a1
  bf16* k      = (bf16*)(ws + 16 * MB);   // live: qkv..a3
  bf16* v      = (bf16*)(ws + 32 * MB);   // live: qkv..conv
  bf16* xn     = (bf16*)(ws + 48 * MB);   // dead after QKV gemm
  bf16* a2_h   = (bf16*)(ws + 48 * MB);   // pinv region overlays xn
  bf16* zh0    = (bf16*)(ws + 52 * MB);
  bf16* zh1    = (bf16*)(ws + 56 * MB);
  bf16* xz_h   = (bf16*)(ws + 60 * MB);
  bf16* t_h    = (bf16*)(ws + 64 * MB);
  bf16* u_h    = (bf16*)(ws + 68 * MB);
  bf16* scores = (bf16*)(ws + 72 * MB);   // 16 MB chunk (8 bh), in-place softmax
  bf16* xattn  = (bf16*)(ws + 72 * MB);   // overlays scores (dead after a1 loop)
  bf16* ql     = (bf16*)(ws + 88 * MB);
  bf16* kl     = (bf16*)(ws + 89 * MB);
  bf16* a3v    = (bf16*)(ws + 90 * MB);
  bf16* W      = (bf16*)(ws + 91 * MB);
  bf16* attn   = (bf16*)(ws + 48 * MB);   // overlays pinv region (dead after W gemm)
  bf16* wqkv_h = (bf16*)(ws + 92 * MB);   // 1.5 MB
  bf16* wout_h = (bf16*)(ws + 94 * MB);   // 0.5 MB
  float* scal  = (float*)(ws + 95 * MB);
  bf16* zh[2] = {zh0, zh1};

  // 0. cast weights fp32 -> bf16
  f2b_kernel<<<384, 256, 0, stream>>>(w_qkv, wqkv_h);   // 786432 = 384*2048
  f2b_kernel<<<128, 256, 0, stream>>>(w_out, wout_h);   // 262144 = 128*2048

  // 1. LayerNorm
  ln_kernel<<<16384, 64, 0, stream>>>(x, ln_w, ln_b, xn);

  // 2. QKV projection, scatter into [b,h,n,d], q scaled
  gemm_k<128, 128, false, MODE_QKV><<<dim3(128, 12, 1), 256, 0, stream>>>(
      xn, wqkv_h, nullptr, 16384, 1536, 512, 0, 0, 0, 1.f, nullptr, nullptr, q, k, v);

  // 3. landmark means
  lm_kernel<<<dim3(32, 256), 64, 0, stream>>>(q, k, ql, kl);

  // 4. a2 = softmax(ql @ kl^T)
  gemm_k<128, 128, true, MODE_BF16><<<dim3(2, 2, 32), 256, 0, stream>>>(
      ql, kl, a2_h, 256, 256, 64, 16384, 16384, 65536, 1.f, nullptr, nullptr, nullptr, nullptr, nullptr);
  softmax256<<<8192, 256, 0, stream>>>(a2_h);

  // 5. z0 = a2^T / (max rowsum * max colsum)
  init_scal<<<1, 1, 0, stream>>>(scal);
  red_row<<<8192, 64, 0, stream>>>(a2_h, scal);
  red_col<<<dim3(32, 4), 64, 0, stream>>>(a2_h, scal);
  z0_k<<<dim3(32, 256), 256, 0, stream>>>(a2_h, scal, zh0);

  // 6. Newton-Schulz x6 : z = 0.25 z (13I - xz(15I - xz(7I - xz)))
  int cur = 0;
  for (int it = 0; it < 6; it++) {
    gemm_k<128, 128, false, MODE_BF16><<<dim3(2, 2, 32), 256, 0, stream>>>(
        a2_h, zh[cur], xz_h, 256, 256, 256, 65536, 65536, 65536, 1.f, nullptr, nullptr, nullptr, nullptr, nullptr);
    ew_diag<<<dim3(32, 256), 256, 0, stream>>>(7.f, xz_h, t_h);
    gemm_k<128, 128, false, MODE_BF16><<<dim3(2, 2, 32), 256, 0, stream>>>(
        xz_h, t_h, u_h, 256, 256, 256, 65536, 65536, 65536, 1.f, nullptr, nullptr, nullptr, nullptr, nullptr);
    ew_diag<<<dim3(32, 256), 256, 0, stream>>>(15.f, u_h, t_h);
    gemm_k<128, 128, false, MODE_BF16><<<dim3(2, 2, 32), 256, 0, stream>>>(
        xz_h, t_h, u_h, 256, 256, 256, 65536, 65536, 65536, 1.f, nullptr, nullptr, nullptr, nullptr, nullptr);
    ew_diag<<<dim3(32, 256), 256, 0, stream>>>(13.f, u_h, t_h);
    gemm_k<128, 128, false, MODE_BF16><<<dim3(2, 2, 32), 256, 0, stream>>>(
        zh[cur], t_h, zh[1 - cur], 256, 256, 256, 65536, 65536, 65536, 0.25f, nullptr, nullptr, nullptr, nullptr, nullptr);
    cur ^= 1;
  }

  // 7. a3 = softmax(ql @ k^T); a3v = a3 @ v   (chunks of 8 bh)
  for (int ch = 0; ch < 4; ch++) {
    long o64 = (long)ch * 8 * 4096 * 64, o16 = (long)ch * 8 * 256 * 64;
    gemm_k<128, 128, true, MODE_BF16><<<dim3(2, 32, 8), 256, 0, stream>>>(
        ql + o16, k + o64, scores, 256, 4096, 64, 16384, 262144, 1048576, 1.f, nullptr, nullptr, nullptr, nullptr, nullptr);
    softmax4096<<<2048, 256, 0, stream>>>(scores);
    gemm_k<128, 64, false, MODE_BF16><<<dim3(2, 1, 8), 256, 0, stream>>>(
        scores, v + o64, a3v + o16, 256, 64, 4096, 1048576, 262144, 16384, 1.f, nullptr, nullptr, nullptr, nullptr, nullptr);
  }

  // 8. W = a2inv @ a3v
  gemm_k<128, 64, false, MODE_BF16><<<dim3(2, 1, 32), 256, 0, stream>>>(
      zh[cur], a3v, W, 256, 64, 256, 65536, 16384, 16384, 1.f, nullptr, nullptr, nullptr, nullptr, nullptr);

  // 9. a1 = softmax(q @ kl^T); attn = a1 @ W   (chunks of 8 bh)
  for (int ch = 0; ch < 4; ch++) {
    long o64 = (long)ch * 8 * 4096 * 64, o16 = (long)ch * 8 * 256 * 64;
    gemm_k<128, 128, true, MODE_BF16><<<dim3(32, 2, 8), 256, 0, stream>>>(
        q + o64, kl + o16, scores, 4096, 256, 64, 262144, 16384, 1048576, 1.f, nullptr, nullptr, nullptr, nullptr, nullptr);
    softmax256<<<32768, 256, 0, stream>>>(scores);
    gemm_k<128, 64, false, MODE_BF16><<<dim3(32, 1, 8), 256, 0, stream>>>(
        scores, W + o16, attn + o64, 4096, 64, 256, 1048576, 16384, 262144, 1.f, nullptr, nullptr, nullptr, nullptr, nullptr);
  }

  // 10. depthwise conv residual + reorder to [b,n,h*d]
  conv_combine<<<dim3(32, 64), 256, 0, stream>>>(attn, v, w_conv, xattn);

  // 11. out = x + xattn @ w_out + b_out   (fp32 out)
  gemm_k<128, 128, false, MODE_RESID><<<dim3(128, 4, 1), 256, 0, stream>>>(
      xattn, wout_h, out, 16384, 512, 512, 0, 0, 0, 1.f, x, b_out, nullptr, nullptr, nullptr);
}

// Round 4
// 789.531 us; speedup vs baseline: 2.3559x; 2.3559x over previous
//
#include <hip/hip_runtime.h>
#include <cstdint>

typedef __bf16 bf16;
typedef __bf16 bf16x8 __attribute__((ext_vector_type(8)));
typedef float  f32x4  __attribute__((ext_vector_type(4)));

// ---------------- fp32 -> bf16 cast (n multiple of 2048) ----------------
__global__ __launch_bounds__(256) void f2b_kernel(const float* __restrict__ in, bf16* __restrict__ out) {
  long i = ((long)blockIdx.x * 256 + threadIdx.x) * 8;
  float4 a = *(const float4*)(in + i);
  float4 b = *(const float4*)(in + i + 4);
  bf16 o[8] = {(bf16)a.x, (bf16)a.y, (bf16)a.z, (bf16)a.w,
               (bf16)b.x, (bf16)b.y, (bf16)b.z, (bf16)b.w};
  *(uint4*)(out + i) = *(uint4*)o;
}

// ---------------- LayerNorm (fp32 in, bf16 out): one wave per row of 512 ----------------
__global__ __launch_bounds__(64) void ln_kernel(const float* __restrict__ x,
    const float* __restrict__ w, const float* __restrict__ b, bf16* __restrict__ xn) {
  long row = blockIdx.x;
  int t = threadIdx.x;
  const float* rp = x + row * 512 + t * 8;
  float4 p0 = *(const float4*)rp;
  float4 p1 = *(const float4*)(rp + 4);
  float vals[8] = {p0.x, p0.y, p0.z, p0.w, p1.x, p1.y, p1.z, p1.w};
  float s = 0.f, s2 = 0.f;
#pragma unroll
  for (int e = 0; e < 8; e++) { s += vals[e]; s2 += vals[e] * vals[e]; }
#pragma unroll
  for (int o = 32; o > 0; o >>= 1) { s += __shfl_xor(s, o); s2 += __shfl_xor(s2, o); }
  float mu = s * (1.f / 512.f);
  float var = s2 * (1.f / 512.f) - mu * mu;
  float rstd = rsqrtf(var + 1e-5f);
  float4 w0 = *(const float4*)(w + t * 8), w1 = *(const float4*)(w + t * 8 + 4);
  float4 b0 = *(const float4*)(b + t * 8), b1 = *(const float4*)(b + t * 8 + 4);
  float wv[8] = {w0.x, w0.y, w0.z, w0.w, w1.x, w1.y, w1.z, w1.w};
  float bv[8] = {b0.x, b0.y, b0.z, b0.w, b1.x, b1.y, b1.z, b1.w};
  bf16 outv[8];
#pragma unroll
  for (int e = 0; e < 8; e++) outv[e] = (bf16)((vals[e] - mu) * rstd * wv[e] + bv[e]);
  *(uint4*)(xn + row * 512 + t * 8) = *(uint4*)outv;
}

// ---------------- batched MFMA GEMM ----------------
// C = alpha * A @ op(B); epilogue variants fused via MODE.
enum { MODE_BF16 = 1, MODE_QKV = 2, MODE_RESID = 3, MODE_XZ = 4, MODE_DIAG = 5 };

template <int BM, int BN, bool BT, int MODE>
__global__ __launch_bounds__(256) void gemm_k(
    const bf16* __restrict__ A, const bf16* __restrict__ B, void* __restrict__ C,
    int M, int N, int K, long sA, long sB, long sC, float alpha, float cdiag,
    const float* __restrict__ resid, const float* __restrict__ bias,
    bf16* __restrict__ aux0, bf16* __restrict__ aux1, bf16* __restrict__ aux2) {
  constexpr int BK = 32, LDST = 40;  // 80B row stride: 16B-aligned, non-pow2
  __shared__ __align__(16) bf16 As[BM * LDST];
  __shared__ __align__(16) bf16 Bs[BN * LDST];
  const int tid = threadIdx.x, lane = tid & 63, wave = tid >> 6;
  const int quad = lane >> 4, l16 = lane & 15;
  constexpr int WN = (BN >= 128) ? 2 : 1;
  constexpr int WM = 4 / WN;
  constexpr int TM = BM / (WM * 16), TN = BN / (WN * 16);
  const int wm0 = (wave / WN) * (BM / WM);
  const int wn0 = (wave % WN) * (BN / WN);
  const int bm0 = blockIdx.x * BM, bn0 = blockIdx.y * BN;
  const bf16* Ab = A + (long)blockIdx.z * sA;
  const bf16* Bb = B + (long)blockIdx.z * sB;

  f32x4 zero = {0.f, 0.f, 0.f, 0.f};
  f32x4 acc[TM][TN];
#pragma unroll
  for (int i = 0; i < TM; i++)
#pragma unroll
    for (int j = 0; j < TN; j++) acc[i][j] = zero;

  for (int k0 = 0; k0 < K; k0 += BK) {
    for (int c = tid; c < BM * 4; c += 256) {
      int r = c >> 2, cv = (c & 3) * 8;
      *(uint4*)&As[r * LDST + cv] = *(const uint4*)&Ab[(long)(bm0 + r) * K + k0 + cv];
    }
    if (BT) {
      for (int c = tid; c < BN * 4; c += 256) {
        int r = c >> 2, cv = (c & 3) * 8;
        *(uint4*)&Bs[r * LDST + cv] = *(const uint4*)&Bb[(long)(bn0 + r) * K + k0 + cv];
      }
    } else {
      for (int c = tid; c < BN * 4; c += 256) {
        int kk = c / (BN / 8), nv = (c % (BN / 8)) * 8;
        uint4 tmp = *(const uint4*)&Bb[(long)(k0 + kk) * N + bn0 + nv];
        const bf16* tv = (const bf16*)&tmp;
#pragma unroll
        for (int e = 0; e < 8; e++) Bs[(nv + e) * LDST + kk] = tv[e];
      }
    }
    __syncthreads();
    bf16x8 af[TM], bfr[TN];
#pragma unroll
    for (int i = 0; i < TM; i++)
      af[i] = *(const bf16x8*)&As[(wm0 + i * 16 + l16) * LDST + quad * 8];
#pragma unroll
    for (int j = 0; j < TN; j++)
      bfr[j] = *(const bf16x8*)&Bs[(wn0 + j * 16 + l16) * LDST + quad * 8];
#pragma unroll
    for (int i = 0; i < TM; i++)
#pragma unroll
      for (int j = 0; j < TN; j++)
        acc[i][j] = __builtin_amdgcn_mfma_f32_16x16x32_bf16(af[i], bfr[j], acc[i][j], 0, 0, 0);
    __syncthreads();
  }

  const long cb = (long)blockIdx.z * sC;
#pragma unroll
  for (int i = 0; i < TM; i++)
#pragma unroll
    for (int j = 0; j < TN; j++)
#pragma unroll
      for (int r = 0; r < 4; r++) {
        int row = bm0 + wm0 + i * 16 + quad * 4 + r;   // C/D: row = quad*4+reg
        int col = bn0 + wn0 + j * 16 + l16;            //      col = lane&15
        float v = acc[i][j][r] * alpha;
        if (MODE == MODE_BF16) {
          ((bf16*)C)[cb + (long)row * N + col] = (bf16)v;
        } else if (MODE == MODE_QKV) {
          int b = row >> 12, n = row & 4095;
          int which = col >> 9, h = (col >> 6) & 7, d = col & 63;
          long o = ((long)(b * 8 + h) * 4096 + n) * 64 + d;
          if (which == 0) aux0[o] = (bf16)(v * 0.125f);  // q * DH^-0.5
          else if (which == 1) aux1[o] = (bf16)v;
          else aux2[o] = (bf16)v;
        } else if (MODE == MODE_XZ) {      // aux0 = xz, aux1 = 7I - xz
          long o = cb + (long)row * N + col;
          aux0[o] = (bf16)v;
          aux1[o] = (bf16)(((row == col) ? cdiag : 0.f) - v);
        } else if (MODE == MODE_DIAG) {    // C = cdiag*I - acc
          ((bf16*)C)[cb + (long)row * N + col] = (bf16)(((row == col) ? cdiag : 0.f) - v);
        } else {  // MODE_RESID: fp32 out = acc + bias + x
          long o = (long)row * N + col;
          ((float*)C)[o] = v + bias[col] + resid[o];
        }
      }
}

// ---------------- landmark means (16 tokens per landmark) ----------------
__global__ __launch_bounds__(64) void lm_kernel(const bf16* __restrict__ q, const bf16* __restrict__ k,
                                                bf16* __restrict__ ql, bf16* __restrict__ kl) {
  int bh = blockIdx.x, mi = blockIdx.y, d = threadIdx.x;
  long base = ((long)bh * 4096 + mi * 16) * 64 + d;
  float sq = 0.f, sk = 0.f;
#pragma unroll
  for (int j = 0; j < 16; j++) { sq += (float)q[base + j * 64]; sk += (float)k[base + j * 64]; }
  long o = ((long)bh * 256 + mi) * 64 + d;
  ql[o] = (bf16)(sq * (1.f / 16.f));
  kl[o] = (bf16)(sk * (1.f / 16.f));
}

// ---------------- in-place softmax over 256 cols (for a2) ----------------
__global__ __launch_bounds__(256) void softmax256(bf16* __restrict__ buf) {
  long row = blockIdx.x;
  int t = threadIdx.x, lane = t & 63, wave = t >> 6;
  __shared__ float sm[4];
  float v = (float)buf[row * 256 + t];
  float m = v;
#pragma unroll
  for (int o = 32; o > 0; o >>= 1) m = fmaxf(m, __shfl_xor(m, o));
  if (lane == 0) sm[wave] = m;
  __syncthreads();
  m = fmaxf(fmaxf(sm[0], sm[1]), fmaxf(sm[2], sm[3]));
  float e = __expf(v - m);
  __syncthreads();
  float s = e;
#pragma unroll
  for (int o = 32; o > 0; o >>= 1) s += __shfl_xor(s, o);
  if (lane == 0) sm[wave] = s;
  __syncthreads();
  s = sm[0] + sm[1] + sm[2] + sm[3];
  buf[row * 256 + t] = (bf16)(e / s);
}

// ---------------- pinv scale helpers ----------------
__global__ void init_scal(float* scal) { ((int*)scal)[0] = 0; ((int*)scal)[1] = 0; }

__global__ __launch_bounds__(64) void red_row(const bf16* __restrict__ a2h, float* scal) {
  long row = blockIdx.x;
  int t = threadIdx.x;
  float s = 0.f;
#pragma unroll
  for (int c = 0; c < 4; c++) s += (float)a2h[row * 256 + t + 64 * c];
#pragma unroll
  for (int o = 32; o > 0; o >>= 1) s += __shfl_xor(s, o);
  if (t == 0) atomicMax((int*)scal, __float_as_int(s));
}

__global__ __launch_bounds__(64) void red_col(const bf16* __restrict__ a2h, float* scal) {
  int bh = blockIdx.x;
  int j = blockIdx.y * 64 + threadIdx.x;
  float s = 0.f;
  const bf16* p = a2h + (long)bh * 65536 + j;
  for (int i = 0; i < 256; i++) s += (float)p[i * 256];
  atomicMax((int*)scal + 1, __float_as_int(s));
}

__global__ __launch_bounds__(256) void z0_k(const bf16* __restrict__ a2h,
                                            const float* __restrict__ scal, bf16* __restrict__ z) {
  int bh = blockIdx.x, i = blockIdx.y, j = threadIdx.x;
  float inv = 1.f / (scal[0] * scal[1]);
  float v = (float)a2h[((long)bh * 256 + i) * 256 + j];
  z[((long)bh * 256 + j) * 256 + i] = (bf16)(v * inv);
}

// ---------------- W transpose: [32][256][64] -> [32][64][256] ----------------
__global__ __launch_bounds__(256) void wt_k(const bf16* __restrict__ W, bf16* __restrict__ WT) {
  int bh = blockIdx.x, tid = threadIdx.x;
  const bf16* wb = W + (long)bh * 16384;
  bf16* wtb = WT + (long)bh * 16384;
  for (int i = tid; i < 2048; i += 256) {
    int n = i >> 3, d8 = (i & 7) * 8;
    uint4 pk = *(const uint4*)&wb[n * 64 + d8];
    const bf16* pv = (const bf16*)&pk;
#pragma unroll
    for (int e = 0; e < 8; e++) wtb[(d8 + e) * 256 + n] = pv[e];
  }
}

// ---------------- F3: fused a3-softmax @ v, n-split partials ----------------
// grid (mt=2, ns=8, bh=32). Rows m0=mt*128 (wave owns 32 rows), n-range ns*512.
// Softmax over n is shift-invariant; |S|<~2 so exp without max-subtract is exact-safe.
// Opart[bh][ns][m][d] = sum_n exp(S) * v ; lpart[bh][ns][m] = sum_n exp(S)
__global__ __launch_bounds__(256) void f3_partial(const bf16* __restrict__ ql,
    const bf16* __restrict__ k, const bf16* __restrict__ v,
    float* __restrict__ Opart, float* __restrict__ lpart) {
  const int mt = blockIdx.x, ns = blockIdx.y, bh = blockIdx.z;
  const int tid = threadIdx.x, lane = tid & 63, wave = tid >> 6;
  const int quad = lane >> 4, l16 = lane & 15;
  const int wr0 = mt * 128 + wave * 32;
  __shared__ __align__(16) bf16 vT[64][72];       // v-chunk transposed [d][n]
  __shared__ __align__(16) bf16 Pts[4][32][72];   // per-wave P [m][n]

  const bf16* qlb = ql + (long)bh * 16384;
  const bf16* kb  = k + (long)bh * 262144;
  const bf16* vb  = v + (long)bh * 262144;

  bf16x8 aq[2][2];
#pragma unroll
  for (int ti = 0; ti < 2; ti++)
#pragma unroll
    for (int ki = 0; ki < 2; ki++)
      aq[ti][ki] = *(const bf16x8*)&qlb[(wr0 + ti * 16 + l16) * 64 + ki * 32 + quad * 8];

  f32x4 zero = {0.f, 0.f, 0.f, 0.f};
  f32x4 Oacc[2][4];
#pragma unroll
  for (int i = 0; i < 2; i++)
#pragma unroll
    for (int j = 0; j < 4; j++) Oacc[i][j] = zero;
  float lacc[2][4] = {};

  for (int c = 0; c < 8; c++) {
    int n0c = ns * 512 + c * 64;
    __syncthreads();   // protect vT from previous iteration's readers
    for (int i = tid; i < 512; i += 256) {
      int nn = i >> 3, d8 = (i & 7) * 8;
      uint4 pk = *(const uint4*)&vb[(long)(n0c + nn) * 64 + d8];
      const bf16* pv = (const bf16*)&pk;
#pragma unroll
      for (int e = 0; e < 8; e++) vT[d8 + e][nn] = pv[e];
    }
    __syncthreads();

    // S = ql_tile @ k_chunk^T   (B-frags straight from global, L2-hot)
    f32x4 sacc[2][4];
#pragma unroll
    for (int i = 0; i < 2; i++)
#pragma unroll
      for (int j = 0; j < 4; j++) sacc[i][j] = zero;
#pragma unroll
    for (int ki = 0; ki < 2; ki++) {
      bf16x8 bk[4];
#pragma unroll
      for (int tj = 0; tj < 4; tj++)
        bk[tj] = *(const bf16x8*)&kb[(long)(n0c + tj * 16 + l16) * 64 + ki * 32 + quad * 8];
#pragma unroll
      for (int ti = 0; ti < 2; ti++)
#pragma unroll
        for (int tj = 0; tj < 4; tj++)
          sacc[ti][tj] = __builtin_amdgcn_mfma_f32_16x16x32_bf16(aq[ti][ki], bk[tj], sacc[ti][tj], 0, 0, 0);
    }
    // exp, accumulate row sums, stage P (wave-local; no barrier needed)
#pragma unroll
    for (int ti = 0; ti < 2; ti++)
#pragma unroll
      for (int tj = 0; tj < 4; tj++)
#pragma unroll
        for (int r = 0; r < 4; r++) {
          float e = __expf(sacc[ti][tj][r]);
          lacc[ti][r] += e;
          Pts[wave][ti * 16 + quad * 4 + r][tj * 16 + l16] = (bf16)e;
        }
    // O += P @ v_chunk
#pragma unroll
    for (int ki = 0; ki < 2; ki++) {
      bf16x8 ap[2], bv[4];
#pragma unroll
      for (int ti = 0; ti < 2; ti++)
        ap[ti] = *(const bf16x8*)&Pts[wave][ti * 16 + l16][ki * 32 + quad * 8];
#pragma unroll
      for (int tj = 0; tj < 4; tj++)
        bv[tj] = *(const bf16x8*)&vT[tj * 16 + l16][ki * 32 + quad * 8];
#pragma unroll
      for (int ti = 0; ti < 2; ti++)
#pragma unroll
        for (int tj = 0; tj < 4; tj++)
          Oacc[ti][tj] = __builtin_amdgcn_mfma_f32_16x16x32_bf16(ap[ti], bv[tj], Oacc[ti][tj], 0, 0, 0);
    }
  }

  // reduce l over the 16 lanes of each row, write partials
#pragma unroll
  for (int ti = 0; ti < 2; ti++)
#pragma unroll
    for (int r = 0; r < 4; r++) {
#pragma unroll
      for (int o = 1; o < 16; o <<= 1) lacc[ti][r] += __shfl_xor(lacc[ti][r], o);
    }
  long pb = ((long)bh * 8 + ns) * 256;
#pragma unroll
  for (int ti = 0; ti < 2; ti++)
#pragma unroll
    for (int r = 0; r < 4; r++) {
      int row = wr0 + ti * 16 + quad * 4 + r;
      if (l16 == 0) lpart[pb + row] = lacc[ti][r];
#pragma unroll
      for (int tj = 0; tj < 4; tj++)
        Opart[(pb + row) * 64 + tj * 16 + l16] = Oacc[ti][tj][r];
    }
}

// combine 8 n-split partials -> a3v bf16 [32][256][64]
__global__ __launch_bounds__(256) void f3_combine(const float* __restrict__ Opart,
    const float* __restrict__ lpart, bf16* __restrict__ a3v) {
  int row = blockIdx.x * 4 + (threadIdx.x >> 6);   // bh*256+m
  int d = threadIdx.x & 63;
  int bh = row >> 8, m = row & 255;
  float so = 0.f, sl = 0.f;
#pragma unroll
  for (int s = 0; s < 8; s++) {
    long pb = ((long)bh * 8 + s) * 256 + m;
    so += Opart[pb * 64 + d];
    sl += lpart[pb];
  }
  a3v[(long)row * 64 + d] = (bf16)(so / sl);
}

// ---------------- F1: fused a1-softmax @ W + depthwise conv + reorder ----------------
// grid (nt=64, bh=32): 64 q-rows per block, all 256 landmark cols.
// out xattn[b][n][h*64+d] = (softmax_m(q@kl^T) @ W)/l + conv(v)
__global__ __launch_bounds__(256) void f1_attn(const bf16* __restrict__ q,
    const bf16* __restrict__ kl, const bf16* __restrict__ WT, const bf16* __restrict__ v,
    const float* __restrict__ wconv, bf16* __restrict__ xattn) {
  const int nt = blockIdx.x, bh = blockIdx.y;
  const int h = bh & 7, b = bh >> 3, n0 = nt * 64;
  const int tid = threadIdx.x, lane = tid & 63, wave = tid >> 6;
  const int quad = lane >> 4, l16 = lane & 15;
  __shared__ __align__(16) bf16 Pts[64][264];
  __shared__ __align__(16) bf16 vs[96][72];
  __shared__ float red[4][64];
  __shared__ float linv[64];
  __shared__ float wcf[33];

  const bf16* qb  = q + (long)bh * 262144;
  const bf16* klb = kl + (long)bh * 16384;
  const bf16* wtb = WT + (long)bh * 16384;
  const bf16* vb  = v + (long)bh * 262144;

  // stage v slice (n0-16 .. n0+80) for conv
  for (int i = tid; i < 768; i += 256) {
    int r = i >> 3, d8 = (i & 7) * 8;
    int n = n0 - 16 + r;
    uint4 val = {0u, 0u, 0u, 0u};
    if (n >= 0 && n < 4096) val = *(const uint4*)&vb[(long)n * 64 + d8];
    *(uint4*)&vs[r][d8] = val;
  }
  if (tid < 33) wcf[tid] = wconv[h * 33 + tid];

  // Phase S: wave covers all 64 rows x its 64 cols. |S| small -> exp w/o max-sub.
  f32x4 zero = {0.f, 0.f, 0.f, 0.f};
  f32x4 sacc[4][4];
#pragma unroll
  for (int i = 0; i < 4; i++)
#pragma unroll
    for (int j = 0; j < 4; j++) sacc[i][j] = zero;
#pragma unroll
  for (int ki = 0; ki < 2; ki++) {
    bf16x8 aq[4], bk[4];
#pragma unroll
    for (int ti = 0; ti < 4; ti++)
      aq[ti] = *(const bf16x8*)&qb[(long)(n0 + ti * 16 + l16) * 64 + ki * 32 + quad * 8];
#pragma unroll
    for (int tj = 0; tj < 4; tj++)
      bk[tj] = *(const bf16x8*)&klb[(long)(wave * 64 + tj * 16 + l16) * 64 + ki * 32 + quad * 8];
#pragma unroll
    for (int ti = 0; ti < 4; ti++)
#pragma unroll
      for (int tj = 0; tj < 4; tj++)
        sacc[ti][tj] = __builtin_amdgcn_mfma_f32_16x16x32_bf16(aq[ti], bk[tj], sacc[ti][tj], 0, 0, 0);
  }
  float ps[4][4] = {};
#pragma unroll
  for (int ti = 0; ti < 4; ti++)
#pragma unroll
    for (int tj = 0; tj < 4; tj++)
#pragma unroll
      for (int r = 0; r < 4; r++) {
        float e = __expf(sacc[ti][tj][r]);
        ps[ti][r] += e;
        Pts[ti * 16 + quad * 4 + r][wave * 64 + tj * 16 + l16] = (bf16)e;
      }
#pragma unroll
  for (int ti = 0; ti < 4; ti++)
#pragma unroll
    for (int r = 0; r < 4; r++) {
#pragma unroll
      for (int o = 1; o < 16; o <<= 1) ps[ti][r] += __shfl_xor(ps[ti][r], o);
      if (l16 == 0) red[wave][ti * 16 + quad * 4 + r] = ps[ti][r];
    }
  __syncthreads();
  if (tid < 64) linv[tid] = 1.f / (red[0][tid] + red[1][tid] + red[2][tid] + red[3][tid]);
  __syncthreads();

  // Phase PV: wave owns 16 rows; K=256 over P rows from LDS, W^T from global
  const int r0 = wave * 16;
  f32x4 Oacc[4];
#pragma unroll
  for (int j = 0; j < 4; j++) Oacc[j] = zero;
#pragma unroll
  for (int ki = 0; ki < 8; ki++) {
    bf16x8 ap = *(const bf16x8*)&Pts[r0 + l16][ki * 32 + quad * 8];
    bf16x8 bw[4];
#pragma unroll
    for (int tj = 0; tj < 4; tj++)
      bw[tj] = *(const bf16x8*)&wtb[(long)(tj * 16 + l16) * 256 + ki * 32 + quad * 8];
#pragma unroll
    for (int tj = 0; tj < 4; tj++)
      Oacc[tj] = __builtin_amdgcn_mfma_f32_16x16x32_bf16(ap, bw[tj], Oacc[tj], 0, 0, 0);
  }

  // Epilogue: normalize, add depthwise conv of v, write [b][n][h*64+d]
#pragma unroll
  for (int rr = 0; rr < 4; rr++) {
    int row = r0 + quad * 4 + rr;
    float inv = linv[row];
    int n = n0 + row;
#pragma unroll
    for (int tj = 0; tj < 4; tj++) {
      int d = tj * 16 + l16;
      float acc = Oacc[tj][rr] * inv;
#pragma unroll
      for (int kk = 0; kk < 33; kk++) acc += (float)vs[row + kk][d] * wcf[kk];
      xattn[(((long)b * 4096 + n) << 9) + (h << 6) + d] = (bf16)acc;
    }
  }
}

// ---------------- host ----------------
extern "C" void kernel_launch(void* const* d_in, const int* in_sizes, int n_in,
                              void* d_out, int out_size, void* d_ws, size_t ws_size,
                              hipStream_t stream) {
  (void)in_sizes; (void)n_in; (void)out_size; (void)ws_size;
  const float* x      = (const float*)d_in[0];
  const float* ln_w   = (const float*)d_in[1];
  const float* ln_b   = (const float*)d_in[2];
  const float* w_qkv  = (const float*)d_in[3];
  const float* w_out  = (const float*)d_in[4];
  const float* b_out  = (const float*)d_in[5];
  const float* w_conv = (const float*)d_in[6];
  float* out = (float*)d_out;

  // ---- ~94.5 MB workspace; overlays have disjoint lifetimes ----
  char* ws = (char*)d_ws;
  const size_t MB = 1u << 20;
  bf16* q      = (bf16*)(ws + 0 * MB);    // live: qkv .. f1
  bf16* k      = (bf16*)(ws + 16 * MB);   // live: qkv .. f3
  bf16* v      = (bf16*)(ws + 32 * MB);   // live: qkv .. f1
  bf16* xn     = (bf16*)(ws + 48 * MB);   // dead after QKV
  bf16* a2_h   = (bf16*)(ws + 48 * MB);   // NS region overlays xn; dead after NS
  bf16* xz_h   = (bf16*)(ws + 52 * MB);
  bf16* t_h    = (bf16*)(ws + 56 * MB);
  bf16* u_h    = (bf16*)(ws + 60 * MB);
  float* Opart = (float*)(ws + 48 * MB);  // 16 MB, overlays NS region after NS
  float* lpart = (float*)(ws + 64 * MB);  // 1 MB
  bf16* zh0    = (bf16*)(ws + 65 * MB);   // NS scratch
  bf16* zh1    = (bf16*)(ws + 69 * MB);   // z0 + final a2inv (live to W gemm)
  bf16* xattn  = (bf16*)(ws + 73 * MB);   // 16 MB, written by f1
  bf16* wqkv_h = (bf16*)(ws + 73 * MB);   // overlays xattn (dead before f1)
  bf16* wout_h = (bf16*)(ws + 75 * MB);   // NOT in xattn region? -> move below
  bf16* ql     = (bf16*)(ws + 89 * MB);
  bf16* kl     = (bf16*)(ws + 90 * MB);
  bf16* a3v    = (bf16*)(ws + 91 * MB);
  bf16* W      = (bf16*)(ws + 92 * MB);
  bf16* WT     = (bf16*)(ws + 93 * MB);
  wout_h       = (bf16*)(ws + 94 * MB);   // 0.5 MB, live till outproj
  float* scal  = (float*)(ws + 94 * MB + 512 * 1024);
  bf16* zh[2] = {zh1, zh0};               // zh[0]=init z0; final lands back in zh1 after 6 iters

  // 0. cast weights fp32 -> bf16
  f2b_kernel<<<384, 256, 0, stream>>>(w_qkv, wqkv_h);
  f2b_kernel<<<128, 256, 0, stream>>>(w_out, wout_h);

  // 1. LayerNorm
  ln_kernel<<<16384, 64, 0, stream>>>(x, ln_w, ln_b, xn);

  // 2. QKV projection, scatter into [b,h,n,d], q scaled
  gemm_k<128, 128, false, MODE_QKV><<<dim3(128, 12, 1), 256, 0, stream>>>(
      xn, wqkv_h, nullptr, 16384, 1536, 512, 0, 0, 0, 1.f, 0.f, nullptr, nullptr, q, k, v);

  // 3. landmark means
  lm_kernel<<<dim3(32, 256), 64, 0, stream>>>(q, k, ql, kl);

  // 4. a2 = softmax(ql @ kl^T)
  gemm_k<64, 64, true, MODE_BF16><<<dim3(4, 4, 32), 256, 0, stream>>>(
      ql, kl, a2_h, 256, 256, 64, 16384, 16384, 65536, 1.f, 0.f, nullptr, nullptr, nullptr, nullptr, nullptr);
  softmax256<<<8192, 256, 0, stream>>>(a2_h);

  // 5. z0 = a2^T / (max rowsum * max colsum)  -> zh1
  init_scal<<<1, 1, 0, stream>>>(scal);
  red_row<<<8192, 64, 0, stream>>>(a2_h, scal);
  red_col<<<dim3(32, 4), 64, 0, stream>>>(a2_h, scal);
  z0_k<<<dim3(32, 256), 256, 0, stream>>>(a2_h, scal, zh[0]);

  // 6. Newton-Schulz x6, diag-epilogues fused into the GEMMs
  int cur = 0;
  for (int it = 0; it < 6; it++) {
    gemm_k<64, 64, false, MODE_XZ><<<dim3(4, 4, 32), 256, 0, stream>>>(
        a2_h, zh[cur], nullptr, 256, 256, 256, 65536, 65536, 65536, 1.f, 7.f, nullptr, nullptr, xz_h, t_h, nullptr);
    gemm_k<64, 64, false, MODE_DIAG><<<dim3(4, 4, 32), 256, 0, stream>>>(
        xz_h, t_h, u_h, 256, 256, 256, 65536, 65536, 65536, 1.f, 15.f, nullptr, nullptr, nullptr, nullptr, nullptr);
    gemm_k<64, 64, false, MODE_DIAG><<<dim3(4, 4, 32), 256, 0, stream>>>(
        xz_h, u_h, t_h, 256, 256, 256, 65536, 65536, 65536, 1.f, 13.f, nullptr, nullptr, nullptr, nullptr, nullptr);
    gemm_k<64, 64, false, MODE_BF16><<<dim3(4, 4, 32), 256, 0, stream>>>(
        zh[cur], t_h, zh[1 - cur], 256, 256, 256, 65536, 65536, 65536, 0.25f, 0.f, nullptr, nullptr, nullptr, nullptr, nullptr);
    cur ^= 1;
  }
  // after even # of iters, final z is back in zh[0] == zh1

  // 7. fused a3-softmax @ v (n-split partials + combine)
  f3_partial<<<dim3(2, 8, 32), 256, 0, stream>>>(ql, k, v, Opart, lpart);
  f3_combine<<<2048, 256, 0, stream>>>(Opart, lpart, a3v);

  // 8. W = a2inv @ a3v ; transpose for f1
  gemm_k<64, 64, false, MODE_BF16><<<dim3(4, 1, 32), 256, 0, stream>>>(
      zh[cur], a3v, W, 256, 64, 256, 65536, 16384, 16384, 1.f, 0.f, nullptr, nullptr, nullptr, nullptr, nullptr);
  wt_k<<<32, 256, 0, stream>>>(W, WT);

  // 9. fused a1-softmax @ W + conv + reorder -> xattn
  f1_attn<<<dim3(64, 32), 256, 0, stream>>>(q, kl, WT, v, w_conv, xattn);

  // 10. out = x + xattn @ w_out + b_out (fp32)
  gemm_k<128, 128, false, MODE_RESID><<<dim3(128, 4, 1), 256, 0, stream>>>(
      xattn, wout_h, out, 16384, 512, 512, 0, 0, 0, 1.f, 0.f, x, b_out, nullptr, nullptr, nullptr);
}

// Round 6
// 721.665 us; speedup vs baseline: 2.5774x; 1.0940x over previous
//
#include <hip/hip_runtime.h>
#include <cstdint>

typedef __bf16 bf16;
typedef __bf16 bf16x8 __attribute__((ext_vector_type(8)));
typedef float  f32x4  __attribute__((ext_vector_type(4)));

// ---------------- fp32 -> bf16 cast + transpose: in[R][C] -> out[C][R] ----------------
// Trivially parallel, no LDS. Lane handles one (c, r8) chunk: reads 8 strided fp32,
// writes one 16B chunk of out row c.
__global__ __launch_bounds__(256) void f2bT_kernel(const float* __restrict__ in, bf16* __restrict__ out,
                                                   int R, int C) {
  int idx = blockIdx.x * 256 + threadIdx.x;
  int nchunk = R >> 3;
  int r8 = idx & (nchunk - 1), c = idx / nchunk;
  bf16 o[8];
#pragma unroll
  for (int e = 0; e < 8; e++) o[e] = (bf16)in[(long)(r8 * 8 + e) * C + c];
  *(uint4*)(out + (long)c * R + r8 * 8) = *(uint4*)o;
}

// ---------------- LayerNorm (fp32 in, bf16 out): one wave per row of 512 ----------------
__global__ __launch_bounds__(64) void ln_kernel(const float* __restrict__ x,
    const float* __restrict__ w, const float* __restrict__ b, bf16* __restrict__ xn) {
  long row = blockIdx.x;
  int t = threadIdx.x;
  const float* rp = x + row * 512 + t * 8;
  float4 p0 = *(const float4*)rp;
  float4 p1 = *(const float4*)(rp + 4);
  float vals[8] = {p0.x, p0.y, p0.z, p0.w, p1.x, p1.y, p1.z, p1.w};
  float s = 0.f, s2 = 0.f;
#pragma unroll
  for (int e = 0; e < 8; e++) { s += vals[e]; s2 += vals[e] * vals[e]; }
#pragma unroll
  for (int o = 32; o > 0; o >>= 1) { s += __shfl_xor(s, o); s2 += __shfl_xor(s2, o); }
  float mu = s * (1.f / 512.f);
  float var = s2 * (1.f / 512.f) - mu * mu;
  float rstd = rsqrtf(var + 1e-5f);
  float4 w0 = *(const float4*)(w + t * 8), w1 = *(const float4*)(w + t * 8 + 4);
  float4 b0 = *(const float4*)(b + t * 8), b1 = *(const float4*)(b + t * 8 + 4);
  float wv[8] = {w0.x, w0.y, w0.z, w0.w, w1.x, w1.y, w1.z, w1.w};
  float bv[8] = {b0.x, b0.y, b0.z, b0.w, b1.x, b1.y, b1.z, b1.w};
  bf16 outv[8];
#pragma unroll
  for (int e = 0; e < 8; e++) outv[e] = (bf16)((vals[e] - mu) * rstd * wv[e] + bv[e]);
  *(uint4*)(xn + row * 512 + t * 8) = *(uint4*)outv;
}

// ---------------- batched MFMA GEMM ----------------
// C = alpha * A @ op(B); epilogue variants fused via MODE.
// BT=true : B stored [N,K] (C = A @ B^T) -> conflict-free vector staging.
// BT=false: B stored [K,N] -> LDS-transpose staging (known bank conflicts; small GEMMs only).
enum { MODE_BF16 = 1, MODE_QKV = 2, MODE_RESID = 3, MODE_XZ = 4, MODE_DIAG = 5 };

template <int BM, int BN, bool BT, int MODE>
__global__ __launch_bounds__(256) void gemm_k(
    const bf16* __restrict__ A, const bf16* __restrict__ B, void* __restrict__ C,
    int M, int N, int K, long sA, long sB, long sC, float alpha, float cdiag,
    const float* __restrict__ resid, const float* __restrict__ bias,
    bf16* __restrict__ aux0, bf16* __restrict__ aux1, bf16* __restrict__ aux2) {
  constexpr int BK = 32, LDST = 40;  // 80B row stride: 16B-aligned, non-pow2
  __shared__ __align__(16) bf16 As[BM * LDST];
  __shared__ __align__(16) bf16 Bs[BN * LDST];
  const int tid = threadIdx.x, lane = tid & 63, wave = tid >> 6;
  const int quad = lane >> 4, l16 = lane & 15;
  constexpr int WN = (BN >= 128) ? 2 : 1;
  constexpr int WM = 4 / WN;
  constexpr int TM = BM / (WM * 16), TN = BN / (WN * 16);
  const int wm0 = (wave / WN) * (BM / WM);
  const int wn0 = (wave % WN) * (BN / WN);
  const int bm0 = blockIdx.x * BM, bn0 = blockIdx.y * BN;
  const bf16* Ab = A + (long)blockIdx.z * sA;
  const bf16* Bb = B + (long)blockIdx.z * sB;

  f32x4 zero = {0.f, 0.f, 0.f, 0.f};
  f32x4 acc[TM][TN];
#pragma unroll
  for (int i = 0; i < TM; i++)
#pragma unroll
    for (int j = 0; j < TN; j++) acc[i][j] = zero;

  for (int k0 = 0; k0 < K; k0 += BK) {
    for (int c = tid; c < BM * 4; c += 256) {
      int r = c >> 2, cv = (c & 3) * 8;
      *(uint4*)&As[r * LDST + cv] = *(const uint4*)&Ab[(long)(bm0 + r) * K + k0 + cv];
    }
    if (BT) {
      for (int c = tid; c < BN * 4; c += 256) {
        int r = c >> 2, cv = (c & 3) * 8;
        *(uint4*)&Bs[r * LDST + cv] = *(const uint4*)&Bb[(long)(bn0 + r) * K + k0 + cv];
      }
    } else {
      for (int c = tid; c < BN * 4; c += 256) {
        int kk = c / (BN / 8), nv = (c % (BN / 8)) * 8;
        uint4 tmp = *(const uint4*)&Bb[(long)(k0 + kk) * N + bn0 + nv];
        const bf16* tv = (const bf16*)&tmp;
#pragma unroll
        for (int e = 0; e < 8; e++) Bs[(nv + e) * LDST + kk] = tv[e];
      }
    }
    __syncthreads();
    bf16x8 af[TM], bfr[TN];
#pragma unroll
    for (int i = 0; i < TM; i++)
      af[i] = *(const bf16x8*)&As[(wm0 + i * 16 + l16) * LDST + quad * 8];
#pragma unroll
    for (int j = 0; j < TN; j++)
      bfr[j] = *(const bf16x8*)&Bs[(wn0 + j * 16 + l16) * LDST + quad * 8];
#pragma unroll
    for (int i = 0; i < TM; i++)
#pragma unroll
      for (int j = 0; j < TN; j++)
        acc[i][j] = __builtin_amdgcn_mfma_f32_16x16x32_bf16(af[i], bfr[j], acc[i][j], 0, 0, 0);
    __syncthreads();
  }

  const long cb = (long)blockIdx.z * sC;
#pragma unroll
  for (int i = 0; i < TM; i++)
#pragma unroll
    for (int j = 0; j < TN; j++)
#pragma unroll
      for (int r = 0; r < 4; r++) {
        int row = bm0 + wm0 + i * 16 + quad * 4 + r;   // C/D: row = quad*4+reg
        int col = bn0 + wn0 + j * 16 + l16;            //      col = lane&15
        float v = acc[i][j][r] * alpha;
        if (MODE == MODE_BF16) {
          ((bf16*)C)[cb + (long)row * N + col] = (bf16)v;
        } else if (MODE == MODE_QKV) {
          int b = row >> 12, n = row & 4095;
          int which = col >> 9, h = (col >> 6) & 7, d = col & 63;
          long o = ((long)(b * 8 + h) * 4096 + n) * 64 + d;
          if (which == 0) aux0[o] = (bf16)(v * 0.125f);  // q * DH^-0.5
          else if (which == 1) aux1[o] = (bf16)v;
          else aux2[o] = (bf16)v;
        } else if (MODE == MODE_XZ) {      // aux0 = xz, aux1 = 7I - xz
          long o = cb + (long)row * N + col;
          aux0[o] = (bf16)v;
          aux1[o] = (bf16)(((row == col) ? cdiag : 0.f) - v);
        } else if (MODE == MODE_DIAG) {    // C = cdiag*I - acc
          ((bf16*)C)[cb + (long)row * N + col] = (bf16)(((row == col) ? cdiag : 0.f) - v);
        } else {  // MODE_RESID: fp32 out = acc + bias + x
          long o = (long)row * N + col;
          ((float*)C)[o] = v + bias[col] + resid[o];
        }
      }
}

// ---------------- landmark means (16 tokens per landmark) ----------------
__global__ __launch_bounds__(64) void lm_kernel(const bf16* __restrict__ q, const bf16* __restrict__ k,
                                                bf16* __restrict__ ql, bf16* __restrict__ kl) {
  int bh = blockIdx.x, mi = blockIdx.y, d = threadIdx.x;
  long base = ((long)bh * 4096 + mi * 16) * 64 + d;
  float sq = 0.f, sk = 0.f;
#pragma unroll
  for (int j = 0; j < 16; j++) { sq += (float)q[base + j * 64]; sk += (float)k[base + j * 64]; }
  long o = ((long)bh * 256 + mi) * 64 + d;
  ql[o] = (bf16)(sq * (1.f / 16.f));
  kl[o] = (bf16)(sk * (1.f / 16.f));
}

// ---------------- in-place softmax over 256 cols (for a2) ----------------
__global__ __launch_bounds__(256) void softmax256(bf16* __restrict__ buf) {
  long row = blockIdx.x;
  int t = threadIdx.x, lane = t & 63, wave = t >> 6;
  __shared__ float sm[4];
  float v = (float)buf[row * 256 + t];
  float m = v;
#pragma unroll
  for (int o = 32; o > 0; o >>= 1) m = fmaxf(m, __shfl_xor(m, o));
  if (lane == 0) sm[wave] = m;
  __syncthreads();
  m = fmaxf(fmaxf(sm[0], sm[1]), fmaxf(sm[2], sm[3]));
  float e = __expf(v - m);
  __syncthreads();
  float s = e;
#pragma unroll
  for (int o = 32; o > 0; o >>= 1) s += __shfl_xor(s, o);
  if (lane == 0) sm[wave] = s;
  __syncthreads();
  s = sm[0] + sm[1] + sm[2] + sm[3];
  buf[row * 256 + t] = (bf16)(e / s);
}

// ---------------- pinv scale helpers ----------------
__global__ void init_scal(float* scal) { ((int*)scal)[0] = 0; ((int*)scal)[1] = 0; }

__global__ __launch_bounds__(64) void red_row(const bf16* __restrict__ a2h, float* scal) {
  long row = blockIdx.x;
  int t = threadIdx.x;
  float s = 0.f;
#pragma unroll
  for (int c = 0; c < 4; c++) s += (float)a2h[row * 256 + t + 64 * c];
#pragma unroll
  for (int o = 32; o > 0; o >>= 1) s += __shfl_xor(s, o);
  if (t == 0) atomicMax((int*)scal, __float_as_int(s));
}

__global__ __launch_bounds__(64) void red_col(const bf16* __restrict__ a2h, float* scal) {
  int bh = blockIdx.x;
  int j = blockIdx.y * 64 + threadIdx.x;
  float s = 0.f;
  const bf16* p = a2h + (long)bh * 65536 + j;
  for (int i = 0; i < 256; i++) s += (float)p[i * 256];
  atomicMax((int*)scal + 1, __float_as_int(s));
}

__global__ __launch_bounds__(256) void z0_k(const bf16* __restrict__ a2h,
                                            const float* __restrict__ scal, bf16* __restrict__ z) {
  int bh = blockIdx.x, i = blockIdx.y, j = threadIdx.x;
  float inv = 1.f / (scal[0] * scal[1]);
  float v = (float)a2h[((long)bh * 256 + i) * 256 + j];
  z[((long)bh * 256 + j) * 256 + i] = (bf16)(v * inv);
}

// ---------------- W transpose: [32][256][64] -> [32][64][256] ----------------
__global__ __launch_bounds__(256) void wt_k(const bf16* __restrict__ W, bf16* __restrict__ WT) {
  int bh = blockIdx.x, tid = threadIdx.x;
  const bf16* wb = W + (long)bh * 16384;
  bf16* wtb = WT + (long)bh * 16384;
  for (int i = tid; i < 2048; i += 256) {
    int n = i >> 3, d8 = (i & 7) * 8;
    uint4 pk = *(const uint4*)&wb[n * 64 + d8];
    const bf16* pv = (const bf16*)&pk;
#pragma unroll
    for (int e = 0; e < 8; e++) wtb[(d8 + e) * 256 + n] = pv[e];
  }
}

// ---------------- F3: fused a3-softmax @ v, n-split partials ----------------
// grid (mt=2, ns=8, bh=32). Rows m0=mt*128 (wave owns 32 rows), n-range ns*512.
// Softmax over n is shift-invariant; |S|<~2 so exp without max-subtract is exact-safe.
__global__ __launch_bounds__(256) void f3_partial(const bf16* __restrict__ ql,
    const bf16* __restrict__ k, const bf16* __restrict__ v,
    float* __restrict__ Opart, float* __restrict__ lpart) {
  const int mt = blockIdx.x, ns = blockIdx.y, bh = blockIdx.z;
  const int tid = threadIdx.x, lane = tid & 63, wave = tid >> 6;
  const int quad = lane >> 4, l16 = lane & 15;
  const int wr0 = mt * 128 + wave * 32;
  __shared__ __align__(16) bf16 vT[64][72];       // v-chunk transposed [d][n]
  __shared__ __align__(16) bf16 Pts[4][32][72];   // per-wave P [m][n]

  const bf16* qlb = ql + (long)bh * 16384;
  const bf16* kb  = k + (long)bh * 262144;
  const bf16* vb  = v + (long)bh * 262144;

  bf16x8 aq[2][2];
#pragma unroll
  for (int ti = 0; ti < 2; ti++)
#pragma unroll
    for (int ki = 0; ki < 2; ki++)
      aq[ti][ki] = *(const bf16x8*)&qlb[(wr0 + ti * 16 + l16) * 64 + ki * 32 + quad * 8];

  f32x4 zero = {0.f, 0.f, 0.f, 0.f};
  f32x4 Oacc[2][4];
#pragma unroll
  for (int i = 0; i < 2; i++)
#pragma unroll
    for (int j = 0; j < 4; j++) Oacc[i][j] = zero;
  float lacc[2][4] = {};

  for (int c = 0; c < 8; c++) {
    int n0c = ns * 512 + c * 64;
    __syncthreads();   // protect vT from previous iteration's readers
    for (int i = tid; i < 512; i += 256) {
      int nn = i >> 3, d8 = (i & 7) * 8;
      uint4 pk = *(const uint4*)&vb[(long)(n0c + nn) * 64 + d8];
      const bf16* pv = (const bf16*)&pk;
#pragma unroll
      for (int e = 0; e < 8; e++) vT[d8 + e][nn] = pv[e];
    }
    __syncthreads();

    // S = ql_tile @ k_chunk^T   (B-frags straight from global, L2-hot)
    f32x4 sacc[2][4];
#pragma unroll
    for (int i = 0; i < 2; i++)
#pragma unroll
      for (int j = 0; j < 4; j++) sacc[i][j] = zero;
#pragma unroll
    for (int ki = 0; ki < 2; ki++) {
      bf16x8 bk[4];
#pragma unroll
      for (int tj = 0; tj < 4; tj++)
        bk[tj] = *(const bf16x8*)&kb[(long)(n0c + tj * 16 + l16) * 64 + ki * 32 + quad * 8];
#pragma unroll
      for (int ti = 0; ti < 2; ti++)
#pragma unroll
        for (int tj = 0; tj < 4; tj++)
          sacc[ti][tj] = __builtin_amdgcn_mfma_f32_16x16x32_bf16(aq[ti][ki], bk[tj], sacc[ti][tj], 0, 0, 0);
    }
    // exp, accumulate row sums, stage P (wave-local; per-wave LDS is in-order)
#pragma unroll
    for (int ti = 0; ti < 2; ti++)
#pragma unroll
      for (int tj = 0; tj < 4; tj++)
#pragma unroll
        for (int r = 0; r < 4; r++) {
          float e = __expf(sacc[ti][tj][r]);
          lacc[ti][r] += e;
          Pts[wave][ti * 16 + quad * 4 + r][tj * 16 + l16] = (bf16)e;
        }
    // O += P @ v_chunk
#pragma unroll
    for (int ki = 0; ki < 2; ki++) {
      bf16x8 ap[2], bv[4];
#pragma unroll
      for (int ti = 0; ti < 2; ti++)
        ap[ti] = *(const bf16x8*)&Pts[wave][ti * 16 + l16][ki * 32 + quad * 8];
#pragma unroll
      for (int tj = 0; tj < 4; tj++)
        bv[tj] = *(const bf16x8*)&vT[tj * 16 + l16][ki * 32 + quad * 8];
#pragma unroll
      for (int ti = 0; ti < 2; ti++)
#pragma unroll
        for (int tj = 0; tj < 4; tj++)
          Oacc[ti][tj] = __builtin_amdgcn_mfma_f32_16x16x32_bf16(ap[ti], bv[tj], Oacc[ti][tj], 0, 0, 0);
    }
  }

  // reduce l over the 16 lanes of each row, write partials
#pragma unroll
  for (int ti = 0; ti < 2; ti++)
#pragma unroll
    for (int r = 0; r < 4; r++) {
#pragma unroll
      for (int o = 1; o < 16; o <<= 1) lacc[ti][r] += __shfl_xor(lacc[ti][r], o);
    }
  long pb = ((long)bh * 8 + ns) * 256;
#pragma unroll
  for (int ti = 0; ti < 2; ti++)
#pragma unroll
    for (int r = 0; r < 4; r++) {
      int row = wr0 + ti * 16 + quad * 4 + r;
      if (l16 == 0) lpart[pb + row] = lacc[ti][r];
#pragma unroll
      for (int tj = 0; tj < 4; tj++)
        Opart[(pb + row) * 64 + tj * 16 + l16] = Oacc[ti][tj][r];
    }
}

// combine 8 n-split partials -> a3v bf16 [32][256][64]
__global__ __launch_bounds__(256) void f3_combine(const float* __restrict__ Opart,
    const float* __restrict__ lpart, bf16* __restrict__ a3v) {
  int row = blockIdx.x * 4 + (threadIdx.x >> 6);   // bh*256+m
  int d = threadIdx.x & 63;
  int bh = row >> 8, m = row & 255;
  float so = 0.f, sl = 0.f;
#pragma unroll
  for (int s = 0; s < 8; s++) {
    long pb = ((long)bh * 8 + s) * 256 + m;
    so += Opart[pb * 64 + d];
    sl += lpart[pb];
  }
  a3v[(long)row * 64 + d] = (bf16)(so / sl);
}

// ---------------- F1: fused a1-softmax @ W + depthwise conv + reorder ----------------
__global__ __launch_bounds__(256) void f1_attn(const bf16* __restrict__ q,
    const bf16* __restrict__ kl, const bf16* __restrict__ WT, const bf16* __restrict__ v,
    const float* __restrict__ wconv, bf16* __restrict__ xattn) {
  const int nt = blockIdx.x, bh = blockIdx.y;
  const int h = bh & 7, b = bh >> 3, n0 = nt * 64;
  const int tid = threadIdx.x, lane = tid & 63, wave = tid >> 6;
  const int quad = lane >> 4, l16 = lane & 15;
  __shared__ __align__(16) bf16 Pts[64][264];
  __shared__ __align__(16) bf16 vs[96][72];
  __shared__ float red[4][64];
  __shared__ float linv[64];
  __shared__ float wcf[33];

  const bf16* qb  = q + (long)bh * 262144;
  const bf16* klb = kl + (long)bh * 16384;
  const bf16* wtb = WT + (long)bh * 16384;
  const bf16* vb  = v + (long)bh * 262144;

  // stage v slice (n0-16 .. n0+80) for conv
  for (int i = tid; i < 768; i += 256) {
    int r = i >> 3, c8 = (i & 7) * 8;
    int n = n0 - 16 + r;
    uint4 val = {0u, 0u, 0u, 0u};
    if (n >= 0 && n < 4096) val = *(const uint4*)&vb[(long)n * 64 + c8];
    *(uint4*)&vs[r][c8] = val;
  }
  if (tid < 33) wcf[tid] = wconv[h * 33 + tid];

  // Phase S: wave covers all 64 rows x its 64 landmark cols.
  f32x4 zero = {0.f, 0.f, 0.f, 0.f};
  f32x4 sacc[4][4];
#pragma unroll
  for (int i = 0; i < 4; i++)
#pragma unroll
    for (int j = 0; j < 4; j++) sacc[i][j] = zero;
#pragma unroll
  for (int ki = 0; ki < 2; ki++) {
    bf16x8 aq[4], bk[4];
#pragma unroll
    for (int ti = 0; ti < 4; ti++)
      aq[ti] = *(const bf16x8*)&qb[(long)(n0 + ti * 16 + l16) * 64 + ki * 32 + quad * 8];
#pragma unroll
    for (int tj = 0; tj < 4; tj++)
      bk[tj] = *(const bf16x8*)&klb[(long)(wave * 64 + tj * 16 + l16) * 64 + ki * 32 + quad * 8];
#pragma unroll
    for (int ti = 0; ti < 4; ti++)
#pragma unroll
      for (int tj = 0; tj < 4; tj++)
        sacc[ti][tj] = __builtin_amdgcn_mfma_f32_16x16x32_bf16(aq[ti], bk[tj], sacc[ti][tj], 0, 0, 0);
  }
  float ps[4][4] = {};
#pragma unroll
  for (int ti = 0; ti < 4; ti++)
#pragma unroll
    for (int tj = 0; tj < 4; tj++)
#pragma unroll
      for (int r = 0; r < 4; r++) {
        float e = __expf(sacc[ti][tj][r]);
        ps[ti][r] += e;
        Pts[ti * 16 + quad * 4 + r][wave * 64 + tj * 16 + l16] = (bf16)e;
      }
#pragma unroll
  for (int ti = 0; ti < 4; ti++)
#pragma unroll
    for (int r = 0; r < 4; r++) {
#pragma unroll
      for (int o = 1; o < 16; o <<= 1) ps[ti][r] += __shfl_xor(ps[ti][r], o);
      if (l16 == 0) red[wave][ti * 16 + quad * 4 + r] = ps[ti][r];
    }
  __syncthreads();
  if (tid < 64) linv[tid] = 1.f / (red[0][tid] + red[1][tid] + red[2][tid] + red[3][tid]);
  __syncthreads();

  // Phase PV: wave owns 16 rows; K=256 over P rows from LDS, W^T from global
  const int r0 = wave * 16;
  f32x4 Oacc[4];
#pragma unroll
  for (int j = 0; j < 4; j++) Oacc[j] = zero;
#pragma unroll
  for (int ki = 0; ki < 8; ki++) {
    bf16x8 ap = *(const bf16x8*)&Pts[r0 + l16][ki * 32 + quad * 8];
    bf16x8 bw[4];
#pragma unroll
    for (int tj = 0; tj < 4; tj++)
      bw[tj] = *(const bf16x8*)&wtb[(long)(tj * 16 + l16) * 256 + ki * 32 + quad * 8];
#pragma unroll
    for (int tj = 0; tj < 4; tj++)
      Oacc[tj] = __builtin_amdgcn_mfma_f32_16x16x32_bf16(ap, bw[tj], Oacc[tj], 0, 0, 0);
  }

  // Epilogue: normalize, add depthwise conv of v, write [b][n][h*64+d]
#pragma unroll
  for (int rr = 0; rr < 4; rr++) {
    int row = r0 + quad * 4 + rr;
    float inv = linv[row];
    int n = n0 + row;
#pragma unroll
    for (int tj = 0; tj < 4; tj++) {
      int d = tj * 16 + l16;
      float acc = Oacc[tj][rr] * inv;
#pragma unroll
      for (int kk = 0; kk < 33; kk++) acc += (float)vs[row + kk][d] * wcf[kk];
      xattn[(((long)b * 4096 + n) << 9) + (h << 6) + d] = (bf16)acc;
    }
  }
}

// ---------------- host ----------------
extern "C" void kernel_launch(void* const* d_in, const int* in_sizes, int n_in,
                              void* d_out, int out_size, void* d_ws, size_t ws_size,
                              hipStream_t stream) {
  (void)in_sizes; (void)n_in; (void)out_size; (void)ws_size;
  const float* x      = (const float*)d_in[0];
  const float* ln_w   = (const float*)d_in[1];
  const float* ln_b   = (const float*)d_in[2];
  const float* w_qkv  = (const float*)d_in[3];
  const float* w_out  = (const float*)d_in[4];
  const float* b_out  = (const float*)d_in[5];
  const float* w_conv = (const float*)d_in[6];
  float* out = (float*)d_out;

  // ---- ~94.5 MB workspace; overlays have disjoint lifetimes (round-4 proven plan) ----
  char* ws = (char*)d_ws;
  const size_t MB = 1u << 20;
  bf16* q      = (bf16*)(ws + 0 * MB);    // live: qkv .. f1
  bf16* k      = (bf16*)(ws + 16 * MB);   // live: qkv .. f3
  bf16* v      = (bf16*)(ws + 32 * MB);   // live: qkv .. f1
  bf16* xn     = (bf16*)(ws + 48 * MB);   // dead after QKV
  bf16* a2_h   = (bf16*)(ws + 48 * MB);   // NS region overlays xn; dead after NS
  bf16* xz_h   = (bf16*)(ws + 52 * MB);
  bf16* t_h    = (bf16*)(ws + 56 * MB);
  bf16* u_h    = (bf16*)(ws + 60 * MB);
  float* Opart = (float*)(ws + 48 * MB);  // 16 MB, post-NS overlay
  float* lpart = (float*)(ws + 64 * MB);  // 1 MB
  bf16* zh0    = (bf16*)(ws + 65 * MB);   // NS scratch
  bf16* zh1    = (bf16*)(ws + 69 * MB);   // z0 + final a2inv (live to W gemm)
  bf16* xattn  = (bf16*)(ws + 73 * MB);   // 16 MB, written by f1
  bf16* wqkvT  = (bf16*)(ws + 73 * MB);   // 1.5 MB, overlays xattn (dead before f1)
  bf16* ql     = (bf16*)(ws + 89 * MB);
  bf16* kl     = (bf16*)(ws + 90 * MB);
  bf16* a3v    = (bf16*)(ws + 91 * MB);
  bf16* W      = (bf16*)(ws + 92 * MB);
  bf16* WT     = (bf16*)(ws + 93 * MB);
  bf16* woutT  = (bf16*)(ws + 94 * MB);   // 0.5 MB, live till outproj
  float* scal  = (float*)(ws + 94 * MB + 512 * 1024);
  bf16* zh[2] = {zh1, zh0};               // zh[0]=init z0; final back in zh1 after 6 iters

  // 0. cast + transpose weights: wqkvT [1536][512], woutT [512][512]
  f2bT_kernel<<<384, 256, 0, stream>>>(w_qkv, wqkvT, 512, 1536);
  f2bT_kernel<<<128, 256, 0, stream>>>(w_out, woutT, 512, 512);

  // 1. LayerNorm
  ln_kernel<<<16384, 64, 0, stream>>>(x, ln_w, ln_b, xn);

  // 2. QKV projection via BT=true (conflict-free staging), scatter into [b,h,n,d]
  gemm_k<128, 128, true, MODE_QKV><<<dim3(128, 12, 1), 256, 0, stream>>>(
      xn, wqkvT, nullptr, 16384, 1536, 512, 0, 0, 0, 1.f, 0.f, nullptr, nullptr, q, k, v);

  // 3. landmark means
  lm_kernel<<<dim3(32, 256), 64, 0, stream>>>(q, k, ql, kl);

  // 4. a2 = softmax(ql @ kl^T)
  gemm_k<64, 64, true, MODE_BF16><<<dim3(4, 4, 32), 256, 0, stream>>>(
      ql, kl, a2_h, 256, 256, 64, 16384, 16384, 65536, 1.f, 0.f, nullptr, nullptr, nullptr, nullptr, nullptr);
  softmax256<<<8192, 256, 0, stream>>>(a2_h);

  // 5. z0 = a2^T / (max rowsum * max colsum)  -> zh1
  init_scal<<<1, 1, 0, stream>>>(scal);
  red_row<<<8192, 64, 0, stream>>>(a2_h, scal);
  red_col<<<dim3(32, 4), 64, 0, stream>>>(a2_h, scal);
  z0_k<<<dim3(32, 256), 256, 0, stream>>>(a2_h, scal, zh[0]);

  // 6. Newton-Schulz x6, diag-epilogues fused into the GEMMs (round-4 proven)
  int cur = 0;
  for (int it = 0; it < 6; it++) {
    gemm_k<64, 64, false, MODE_XZ><<<dim3(4, 4, 32), 256, 0, stream>>>(
        a2_h, zh[cur], nullptr, 256, 256, 256, 65536, 65536, 65536, 1.f, 7.f, nullptr, nullptr, xz_h, t_h, nullptr);
    gemm_k<64, 64, false, MODE_DIAG><<<dim3(4, 4, 32), 256, 0, stream>>>(
        xz_h, t_h, u_h, 256, 256, 256, 65536, 65536, 65536, 1.f, 15.f, nullptr, nullptr, nullptr, nullptr, nullptr);
    gemm_k<64, 64, false, MODE_DIAG><<<dim3(4, 4, 32), 256, 0, stream>>>(
        xz_h, u_h, t_h, 256, 256, 256, 65536, 65536, 65536, 1.f, 13.f, nullptr, nullptr, nullptr, nullptr, nullptr);
    gemm_k<64, 64, false, MODE_BF16><<<dim3(4, 4, 32), 256, 0, stream>>>(
        zh[cur], t_h, zh[1 - cur], 256, 256, 256, 65536, 65536, 65536, 0.25f, 0.f, nullptr, nullptr, nullptr, nullptr, nullptr);
    cur ^= 1;
  }
  // cur == 0: final pinv in zh[0] == zh1

  // 7. fused a3-softmax @ v (n-split partials + combine)
  f3_partial<<<dim3(2, 8, 32), 256, 0, stream>>>(ql, k, v, Opart, lpart);
  f3_combine<<<2048, 256, 0, stream>>>(Opart, lpart, a3v);

  // 8. W = a2inv @ a3v ; transpose for f1
  gemm_k<64, 64, false, MODE_BF16><<<dim3(4, 1, 32), 256, 0, stream>>>(
      zh[cur], a3v, W, 256, 64, 256, 65536, 16384, 16384, 1.f, 0.f, nullptr, nullptr, nullptr, nullptr, nullptr);
  wt_k<<<32, 256, 0, stream>>>(W, WT);

  // 9. fused a1-softmax @ W + conv + reorder -> xattn
  f1_attn<<<dim3(64, 32), 256, 0, stream>>>(q, kl, WT, v, w_conv, xattn);

  // 10. out = x + xattn @ w_out + b_out (fp32), BT=true conflict-free
  gemm_k<128, 128, true, MODE_RESID><<<dim3(128, 4, 1), 256, 0, stream>>>(
      xattn, woutT, out, 16384, 512, 512, 0, 0, 0, 1.f, 0.f, x, b_out, nullptr, nullptr, nullptr);
}

// Round 7
// 587.838 us; speedup vs baseline: 3.1642x; 1.2277x over previous
//
#include <hip/hip_runtime.h>
#include <cstdint>

typedef __bf16 bf16;
typedef __bf16 bf16x8 __attribute__((ext_vector_type(8)));
typedef float  f32x4  __attribute__((ext_vector_type(4)));

// ---------------- merged weight prep: fp32->bf16 cast+transpose for both weights ----------------
// wqkv [512][1536] -> wqkvT [1536][512]; wout [512][512] -> woutT [512][512]^T
__global__ __launch_bounds__(256) void prep_w(const float* __restrict__ wqkv, const float* __restrict__ wout,
                                              bf16* __restrict__ wqkvT, bf16* __restrict__ woutT) {
  int idx = blockIdx.x * 256 + threadIdx.x;
  if (idx < 98304) {            // 1536 cols x 64 chunks
    int r8 = idx & 63, c = idx >> 6;
    bf16 o[8];
#pragma unroll
    for (int e = 0; e < 8; e++) o[e] = (bf16)wqkv[(long)(r8 * 8 + e) * 1536 + c];
    *(uint4*)(wqkvT + (long)c * 512 + r8 * 8) = *(uint4*)o;
  } else {                      // 512 cols x 64 chunks
    int j = idx - 98304;
    int r8 = j & 63, c = j >> 6;
    bf16 o[8];
#pragma unroll
    for (int e = 0; e < 8; e++) o[e] = (bf16)wout[(long)(r8 * 8 + e) * 512 + c];
    *(uint4*)(woutT + (long)c * 512 + r8 * 8) = *(uint4*)o;
  }
}

// ---------------- LayerNorm (fp32 in, bf16 out): one wave per row of 512 ----------------
__global__ __launch_bounds__(64) void ln_kernel(const float* __restrict__ x,
    const float* __restrict__ w, const float* __restrict__ b, bf16* __restrict__ xn) {
  long row = blockIdx.x;
  int t = threadIdx.x;
  const float* rp = x + row * 512 + t * 8;
  float4 p0 = *(const float4*)rp;
  float4 p1 = *(const float4*)(rp + 4);
  float vals[8] = {p0.x, p0.y, p0.z, p0.w, p1.x, p1.y, p1.z, p1.w};
  float s = 0.f, s2 = 0.f;
#pragma unroll
  for (int e = 0; e < 8; e++) { s += vals[e]; s2 += vals[e] * vals[e]; }
#pragma unroll
  for (int o = 32; o > 0; o >>= 1) { s += __shfl_xor(s, o); s2 += __shfl_xor(s2, o); }
  float mu = s * (1.f / 512.f);
  float var = s2 * (1.f / 512.f) - mu * mu;
  float rstd = rsqrtf(var + 1e-5f);
  float4 w0 = *(const float4*)(w + t * 8), w1 = *(const float4*)(w + t * 8 + 4);
  float4 b0 = *(const float4*)(b + t * 8), b1 = *(const float4*)(b + t * 8 + 4);
  float wv[8] = {w0.x, w0.y, w0.z, w0.w, w1.x, w1.y, w1.z, w1.w};
  float bv[8] = {b0.x, b0.y, b0.z, b0.w, b1.x, b1.y, b1.z, b1.w};
  bf16 outv[8];
#pragma unroll
  for (int e = 0; e < 8; e++) outv[e] = (bf16)((vals[e] - mu) * rstd * wv[e] + bv[e]);
  *(uint4*)(xn + row * 512 + t * 8) = *(uint4*)outv;
}

// ---------------- batched MFMA GEMM ----------------
// C = alpha * A @ op(B); epilogue variants fused via MODE.
enum { MODE_BF16 = 1, MODE_QKV = 2, MODE_RESID = 3, MODE_XZ = 4, MODE_DIAG = 5 };

template <int BM, int BN, bool BT, int MODE>
__global__ __launch_bounds__(256) void gemm_k(
    const bf16* __restrict__ A, const bf16* __restrict__ B, void* __restrict__ C,
    int M, int N, int K, long sA, long sB, long sC, float alpha, float cdiag,
    const float* __restrict__ resid, const float* __restrict__ bias,
    bf16* __restrict__ aux0, bf16* __restrict__ aux1, bf16* __restrict__ aux2) {
  constexpr int BK = 32, LDST = 40;  // 80B row stride: 16B-aligned, non-pow2
  __shared__ __align__(16) bf16 As[BM * LDST];
  __shared__ __align__(16) bf16 Bs[BN * LDST];
  const int tid = threadIdx.x, lane = tid & 63, wave = tid >> 6;
  const int quad = lane >> 4, l16 = lane & 15;
  constexpr int WN = (BN >= 128) ? 2 : 1;
  constexpr int WM = 4 / WN;
  constexpr int TM = BM / (WM * 16), TN = BN / (WN * 16);
  const int wm0 = (wave / WN) * (BM / WM);
  const int wn0 = (wave % WN) * (BN / WN);
  const int bm0 = blockIdx.x * BM, bn0 = blockIdx.y * BN;
  const bf16* Ab = A + (long)blockIdx.z * sA;
  const bf16* Bb = B + (long)blockIdx.z * sB;

  f32x4 zero = {0.f, 0.f, 0.f, 0.f};
  f32x4 acc[TM][TN];
#pragma unroll
  for (int i = 0; i < TM; i++)
#pragma unroll
    for (int j = 0; j < TN; j++) acc[i][j] = zero;

  for (int k0 = 0; k0 < K; k0 += BK) {
    for (int c = tid; c < BM * 4; c += 256) {
      int r = c >> 2, cv = (c & 3) * 8;
      *(uint4*)&As[r * LDST + cv] = *(const uint4*)&Ab[(long)(bm0 + r) * K + k0 + cv];
    }
    if (BT) {
      for (int c = tid; c < BN * 4; c += 256) {
        int r = c >> 2, cv = (c & 3) * 8;
        *(uint4*)&Bs[r * LDST + cv] = *(const uint4*)&Bb[(long)(bn0 + r) * K + k0 + cv];
      }
    } else {
      for (int c = tid; c < BN * 4; c += 256) {
        int kk = c / (BN / 8), nv = (c % (BN / 8)) * 8;
        uint4 tmp = *(const uint4*)&Bb[(long)(k0 + kk) * N + bn0 + nv];
        const bf16* tv = (const bf16*)&tmp;
#pragma unroll
        for (int e = 0; e < 8; e++) Bs[(nv + e) * LDST + kk] = tv[e];
      }
    }
    __syncthreads();
    bf16x8 af[TM], bfr[TN];
#pragma unroll
    for (int i = 0; i < TM; i++)
      af[i] = *(const bf16x8*)&As[(wm0 + i * 16 + l16) * LDST + quad * 8];
#pragma unroll
    for (int j = 0; j < TN; j++)
      bfr[j] = *(const bf16x8*)&Bs[(wn0 + j * 16 + l16) * LDST + quad * 8];
#pragma unroll
    for (int i = 0; i < TM; i++)
#pragma unroll
      for (int j = 0; j < TN; j++)
        acc[i][j] = __builtin_amdgcn_mfma_f32_16x16x32_bf16(af[i], bfr[j], acc[i][j], 0, 0, 0);
    __syncthreads();
  }

  const long cb = (long)blockIdx.z * sC;
#pragma unroll
  for (int i = 0; i < TM; i++)
#pragma unroll
    for (int j = 0; j < TN; j++)
#pragma unroll
      for (int r = 0; r < 4; r++) {
        int row = bm0 + wm0 + i * 16 + quad * 4 + r;   // C/D: row = quad*4+reg
        int col = bn0 + wn0 + j * 16 + l16;            //      col = lane&15
        float v = acc[i][j][r] * alpha;
        if (MODE == MODE_BF16) {
          ((bf16*)C)[cb + (long)row * N + col] = (bf16)v;
        } else if (MODE == MODE_QKV) {
          int b = row >> 12, n = row & 4095;
          int which = col >> 9, h = (col >> 6) & 7, d = col & 63;
          long o = ((long)(b * 8 + h) * 4096 + n) * 64 + d;
          if (which == 0) aux0[o] = (bf16)(v * 0.125f);  // q * DH^-0.5
          else if (which == 1) aux1[o] = (bf16)v;
          else aux2[o] = (bf16)v;
        } else if (MODE == MODE_XZ) {      // aux0 = xz, aux1 = 7I - xz
          long o = cb + (long)row * N + col;
          aux0[o] = (bf16)v;
          aux1[o] = (bf16)(((row == col) ? cdiag : 0.f) - v);
        } else if (MODE == MODE_DIAG) {    // C = cdiag*I - acc
          ((bf16*)C)[cb + (long)row * N + col] = (bf16)(((row == col) ? cdiag : 0.f) - v);
        } else {  // MODE_RESID: fp32 out = acc + bias + x
          long o = (long)row * N + col;
          ((float*)C)[o] = v + bias[col] + resid[o];
        }
      }
}

// ---------------- landmark means (16 tokens per landmark), 4 landmarks per block ----------------
__global__ __launch_bounds__(256) void lm_kernel(const bf16* __restrict__ q, const bf16* __restrict__ k,
                                                 bf16* __restrict__ ql, bf16* __restrict__ kl) {
  int bh = blockIdx.x, mi = blockIdx.y * 4 + (threadIdx.x >> 6), d = threadIdx.x & 63;
  long base = ((long)bh * 4096 + mi * 16) * 64 + d;
  float sq = 0.f, sk = 0.f;
#pragma unroll
  for (int j = 0; j < 16; j++) { sq += (float)q[base + j * 64]; sk += (float)k[base + j * 64]; }
  long o = ((long)bh * 256 + mi) * 64 + d;
  ql[o] = (bf16)(sq * (1.f / 16.f));
  kl[o] = (bf16)(sk * (1.f / 16.f));
}

// ---------------- in-place softmax over 256 cols (for a2) ----------------
__global__ __launch_bounds__(256) void softmax256(bf16* __restrict__ buf) {
  long row = blockIdx.x;
  int t = threadIdx.x, lane = t & 63, wave = t >> 6;
  __shared__ float sm[4];
  float v = (float)buf[row * 256 + t];
  float m = v;
#pragma unroll
  for (int o = 32; o > 0; o >>= 1) m = fmaxf(m, __shfl_xor(m, o));
  if (lane == 0) sm[wave] = m;
  __syncthreads();
  m = fmaxf(fmaxf(sm[0], sm[1]), fmaxf(sm[2], sm[3]));
  float e = __expf(v - m);
  __syncthreads();
  float s = e;
#pragma unroll
  for (int o = 32; o > 0; o >>= 1) s += __shfl_xor(s, o);
  if (lane == 0) sm[wave] = s;
  __syncthreads();
  s = sm[0] + sm[1] + sm[2] + sm[3];
  buf[row * 256 + t] = (bf16)(e / s);
}

// ---------------- pinv scale helpers ----------------
// max row-sum of softmax output == 1 exactly (softmax rows sum to 1); only col-sums need reducing.
__global__ void init_scal(float* scal) { scal[0] = 1.0f; ((int*)scal)[1] = 0; }

__global__ __launch_bounds__(64) void red_col(const bf16* __restrict__ a2h, float* scal) {
  int bh = blockIdx.x;
  int j = blockIdx.y * 64 + threadIdx.x;
  float s = 0.f;
  const bf16* p = a2h + (long)bh * 65536 + j;
  for (int i = 0; i < 256; i++) s += (float)p[i * 256];
  atomicMax((int*)scal + 1, __float_as_int(s));
}

__global__ __launch_bounds__(256) void z0_k(const bf16* __restrict__ a2h,
                                            const float* __restrict__ scal, bf16* __restrict__ z) {
  int bh = blockIdx.x, i = blockIdx.y, j = threadIdx.x;
  float inv = 1.f / (scal[0] * scal[1]);
  float v = (float)a2h[((long)bh * 256 + i) * 256 + j];
  z[((long)bh * 256 + j) * 256 + i] = (bf16)(v * inv);
}

// ---------------- W transpose: [32][256][64] -> [32][64][256] ----------------
__global__ __launch_bounds__(256) void wt_k(const bf16* __restrict__ W, bf16* __restrict__ WT) {
  int bh = blockIdx.x, tid = threadIdx.x;
  const bf16* wb = W + (long)bh * 16384;
  bf16* wtb = WT + (long)bh * 16384;
  for (int i = tid; i < 2048; i += 256) {
    int n = i >> 3, d8 = (i & 7) * 8;
    uint4 pk = *(const uint4*)&wb[n * 64 + d8];
    const bf16* pv = (const bf16*)&pk;
#pragma unroll
    for (int e = 0; e < 8; e++) wtb[(d8 + e) * 256 + n] = pv[e];
  }
}

// ---------------- F3: fused a3-softmax @ v, n-split partials ----------------
__global__ __launch_bounds__(256) void f3_partial(const bf16* __restrict__ ql,
    const bf16* __restrict__ k, const bf16* __restrict__ v,
    float* __restrict__ Opart, float* __restrict__ lpart) {
  const int mt = blockIdx.x, ns = blockIdx.y, bh = blockIdx.z;
  const int tid = threadIdx.x, lane = tid & 63, wave = tid >> 6;
  const int quad = lane >> 4, l16 = lane & 15;
  const int wr0 = mt * 128 + wave * 32;
  __shared__ __align__(16) bf16 vT[64][72];       // v-chunk transposed [d][n]
  __shared__ __align__(16) bf16 Pts[4][32][72];   // per-wave P [m][n]

  const bf16* qlb = ql + (long)bh * 16384;
  const bf16* kb  = k + (long)bh * 262144;
  const bf16* vb  = v + (long)bh * 262144;

  bf16x8 aq[2][2];
#pragma unroll
  for (int ti = 0; ti < 2; ti++)
#pragma unroll
    for (int ki = 0; ki < 2; ki++)
      aq[ti][ki] = *(const bf16x8*)&qlb[(wr0 + ti * 16 + l16) * 64 + ki * 32 + quad * 8];

  f32x4 zero = {0.f, 0.f, 0.f, 0.f};
  f32x4 Oacc[2][4];
#pragma unroll
  for (int i = 0; i < 2; i++)
#pragma unroll
    for (int j = 0; j < 4; j++) Oacc[i][j] = zero;
  float lacc[2][4] = {};

  for (int c = 0; c < 8; c++) {
    int n0c = ns * 512 + c * 64;
    __syncthreads();
    for (int i = tid; i < 512; i += 256) {
      int nn = i >> 3, d8 = (i & 7) * 8;
      uint4 pk = *(const uint4*)&vb[(long)(n0c + nn) * 64 + d8];
      const bf16* pv = (const bf16*)&pk;
#pragma unroll
      for (int e = 0; e < 8; e++) vT[d8 + e][nn] = pv[e];
    }
    __syncthreads();

    f32x4 sacc[2][4];
#pragma unroll
    for (int i = 0; i < 2; i++)
#pragma unroll
      for (int j = 0; j < 4; j++) sacc[i][j] = zero;
#pragma unroll
    for (int ki = 0; ki < 2; ki++) {
      bf16x8 bk[4];
#pragma unroll
      for (int tj = 0; tj < 4; tj++)
        bk[tj] = *(const bf16x8*)&kb[(long)(n0c + tj * 16 + l16) * 64 + ki * 32 + quad * 8];
#pragma unroll
      for (int ti = 0; ti < 2; ti++)
#pragma unroll
        for (int tj = 0; tj < 4; tj++)
          sacc[ti][tj] = __builtin_amdgcn_mfma_f32_16x16x32_bf16(aq[ti][ki], bk[tj], sacc[ti][tj], 0, 0, 0);
    }
#pragma unroll
    for (int ti = 0; ti < 2; ti++)
#pragma unroll
      for (int tj = 0; tj < 4; tj++)
#pragma unroll
        for (int r = 0; r < 4; r++) {
          float e = __expf(sacc[ti][tj][r]);
          lacc[ti][r] += e;
          Pts[wave][ti * 16 + quad * 4 + r][tj * 16 + l16] = (bf16)e;
        }
#pragma unroll
    for (int ki = 0; ki < 2; ki++) {
      bf16x8 ap[2], bv[4];
#pragma unroll
      for (int ti = 0; ti < 2; ti++)
        ap[ti] = *(const bf16x8*)&Pts[wave][ti * 16 + l16][ki * 32 + quad * 8];
#pragma unroll
      for (int tj = 0; tj < 4; tj++)
        bv[tj] = *(const bf16x8*)&vT[tj * 16 + l16][ki * 32 + quad * 8];
#pragma unroll
      for (int ti = 0; ti < 2; ti++)
#pragma unroll
        for (int tj = 0; tj < 4; tj++)
          Oacc[ti][tj] = __builtin_amdgcn_mfma_f32_16x16x32_bf16(ap[ti], bv[tj], Oacc[ti][tj], 0, 0, 0);
    }
  }

#pragma unroll
  for (int ti = 0; ti < 2; ti++)
#pragma unroll
    for (int r = 0; r < 4; r++) {
#pragma unroll
      for (int o = 1; o < 16; o <<= 1) lacc[ti][r] += __shfl_xor(lacc[ti][r], o);
    }
  long pb = ((long)bh * 8 + ns) * 256;
#pragma unroll
  for (int ti = 0; ti < 2; ti++)
#pragma unroll
    for (int r = 0; r < 4; r++) {
      int row = wr0 + ti * 16 + quad * 4 + r;
      if (l16 == 0) lpart[pb + row] = lacc[ti][r];
#pragma unroll
      for (int tj = 0; tj < 4; tj++)
        Opart[(pb + row) * 64 + tj * 16 + l16] = Oacc[ti][tj][r];
    }
}

// combine 8 n-split partials -> a3v bf16 [32][256][64]
__global__ __launch_bounds__(256) void f3_combine(const float* __restrict__ Opart,
    const float* __restrict__ lpart, bf16* __restrict__ a3v) {
  int row = blockIdx.x * 4 + (threadIdx.x >> 6);   // bh*256+m
  int d = threadIdx.x & 63;
  int bh = row >> 8, m = row & 255;
  float so = 0.f, sl = 0.f;
#pragma unroll
  for (int s = 0; s < 8; s++) {
    long pb = ((long)bh * 8 + s) * 256 + m;
    so += Opart[pb * 64 + d];
    sl += lpart[pb];
  }
  a3v[(long)row * 64 + d] = (bf16)(so / sl);
}

// ---------------- F1: fused a1-softmax @ W + Toeplitz-MFMA depthwise conv + reorder ----------------
__global__ __launch_bounds__(256) void f1_attn(const bf16* __restrict__ q,
    const bf16* __restrict__ kl, const bf16* __restrict__ WT, const bf16* __restrict__ v,
    const float* __restrict__ wconv, bf16* __restrict__ xattn) {
  const int nt = blockIdx.x, bh = blockIdx.y;
  const int h = bh & 7, b = bh >> 3, n0 = nt * 64;
  const int tid = threadIdx.x, lane = tid & 63, wave = tid >> 6;
  const int quad = lane >> 4, l16 = lane & 15;
  __shared__ __align__(16) bf16 Pts[64][264];
  __shared__ __align__(16) bf16 vsT[64][104];  // [d][r], r = n - n0 + 16 in [0,96)
  __shared__ float red[4][64];
  __shared__ float linv[64];

  const bf16* qb  = q + (long)bh * 262144;
  const bf16* klb = kl + (long)bh * 16384;
  const bf16* wtb = WT + (long)bh * 16384;
  const bf16* vb  = v + (long)bh * 262144;

  // conv weights held in registers: lane l holds w[l] for l<33
  float wreg = (lane < 33) ? wconv[h * 33 + lane] : 0.f;

  // stage v slice transposed: vsT[d][r] = v[n0-16+r][d] (zero outside [0,4096))
  for (int i = tid; i < 768; i += 256) {
    int r = i >> 3, d8 = (i & 7) * 8;
    int n = n0 - 16 + r;
    uint4 val = {0u, 0u, 0u, 0u};
    if (n >= 0 && n < 4096) val = *(const uint4*)&vb[(long)n * 64 + d8];
    const bf16* pv = (const bf16*)&val;
#pragma unroll
    for (int e = 0; e < 8; e++) vsT[d8 + e][r] = pv[e];
  }

  // Phase S: wave covers all 64 rows x its 64 landmark cols
  f32x4 zero = {0.f, 0.f, 0.f, 0.f};
  f32x4 sacc[4][4];
#pragma unroll
  for (int i = 0; i < 4; i++)
#pragma unroll
    for (int j = 0; j < 4; j++) sacc[i][j] = zero;
#pragma unroll
  for (int ki = 0; ki < 2; ki++) {
    bf16x8 aq[4], bk[4];
#pragma unroll
    for (int ti = 0; ti < 4; ti++)
      aq[ti] = *(const bf16x8*)&qb[(long)(n0 + ti * 16 + l16) * 64 + ki * 32 + quad * 8];
#pragma unroll
    for (int tj = 0; tj < 4; tj++)
      bk[tj] = *(const bf16x8*)&klb[(long)(wave * 64 + tj * 16 + l16) * 64 + ki * 32 + quad * 8];
#pragma unroll
    for (int ti = 0; ti < 4; ti++)
#pragma unroll
      for (int tj = 0; tj < 4; tj++)
        sacc[ti][tj] = __builtin_amdgcn_mfma_f32_16x16x32_bf16(aq[ti], bk[tj], sacc[ti][tj], 0, 0, 0);
  }
  float ps[4][4] = {};
#pragma unroll
  for (int ti = 0; ti < 4; ti++)
#pragma unroll
    for (int tj = 0; tj < 4; tj++)
#pragma unroll
      for (int r = 0; r < 4; r++) {
        float e = __expf(sacc[ti][tj][r]);
        ps[ti][r] += e;
        Pts[ti * 16 + quad * 4 + r][wave * 64 + tj * 16 + l16] = (bf16)e;
      }
#pragma unroll
  for (int ti = 0; ti < 4; ti++)
#pragma unroll
    for (int r = 0; r < 4; r++) {
#pragma unroll
      for (int o = 1; o < 16; o <<= 1) ps[ti][r] += __shfl_xor(ps[ti][r], o);
      if (l16 == 0) red[wave][ti * 16 + quad * 4 + r] = ps[ti][r];
    }
  __syncthreads();
  if (tid < 64) linv[tid] = 1.f / (red[0][tid] + red[1][tid] + red[2][tid] + red[3][tid]);
  __syncthreads();

  // Phase PV: wave owns 16 rows; K=256 over P (LDS) x WT (global)
  const int r0 = wave * 16;
  f32x4 Oacc[4];
#pragma unroll
  for (int j = 0; j < 4; j++) Oacc[j] = zero;
#pragma unroll
  for (int ki = 0; ki < 8; ki++) {
    bf16x8 ap = *(const bf16x8*)&Pts[r0 + l16][ki * 32 + quad * 8];
    bf16x8 bw[4];
#pragma unroll
    for (int tj = 0; tj < 4; tj++)
      bw[tj] = *(const bf16x8*)&wtb[(long)(tj * 16 + l16) * 256 + ki * 32 + quad * 8];
#pragma unroll
    for (int tj = 0; tj < 4; tj++)
      Oacc[tj] = __builtin_amdgcn_mfma_f32_16x16x32_bf16(ap, bw[tj], Oacc[tj], 0, 0, 0);
  }

  // Conv via banded-Toeplitz MFMA: out[m][d] = sum_j w[j-m] * vsT[d][j]
  // A[m=l16][k=quad*8+j] = w[k - r0 - m]; each wave's band touches exactly 2 of 3 k-chunks.
  f32x4 Cacc[4];
#pragma unroll
  for (int j = 0; j < 4; j++) Cacc[j] = zero;
#pragma unroll
  for (int ki = 0; ki < 3; ki++) {
    if (ki * 32 + 31 < r0 || ki * 32 > r0 + 47) continue;   // wave-uniform skip
    bf16x8 av;
#pragma unroll
    for (int j = 0; j < 8; j++) {
      int idx = ki * 32 + quad * 8 + j - r0 - l16;
      float wv = __shfl(wreg, idx & 63);
      av[j] = (idx >= 0 && idx < 33) ? (bf16)wv : (bf16)0.f;
    }
    bf16x8 bv[4];
#pragma unroll
    for (int tj = 0; tj < 4; tj++)
      bv[tj] = *(const bf16x8*)&vsT[tj * 16 + l16][ki * 32 + quad * 8];
#pragma unroll
    for (int tj = 0; tj < 4; tj++)
      Cacc[tj] = __builtin_amdgcn_mfma_f32_16x16x32_bf16(av, bv[tj], Cacc[tj], 0, 0, 0);
  }

  // Epilogue: out = Oacc/l + conv, write [b][n][h*64+d]
#pragma unroll
  for (int rr = 0; rr < 4; rr++) {
    int row = r0 + quad * 4 + rr;
    float inv = linv[row];
    int n = n0 + row;
#pragma unroll
    for (int tj = 0; tj < 4; tj++) {
      int d = tj * 16 + l16;
      xattn[(((long)b * 4096 + n) << 9) + (h << 6) + d] = (bf16)(Oacc[tj][rr] * inv + Cacc[tj][rr]);
    }
  }
}

// ---------------- host ----------------
extern "C" void kernel_launch(void* const* d_in, const int* in_sizes, int n_in,
                              void* d_out, int out_size, void* d_ws, size_t ws_size,
                              hipStream_t stream) {
  (void)in_sizes; (void)n_in; (void)out_size; (void)ws_size;
  const float* x      = (const float*)d_in[0];
  const float* ln_w   = (const float*)d_in[1];
  const float* ln_b   = (const float*)d_in[2];
  const float* w_qkv  = (const float*)d_in[3];
  const float* w_out  = (const float*)d_in[4];
  const float* b_out  = (const float*)d_in[5];
  const float* w_conv = (const float*)d_in[6];
  float* out = (float*)d_out;

  // ---- ~94.5 MB workspace; overlays have disjoint lifetimes (round-4/6 proven plan) ----
  char* ws = (char*)d_ws;
  const size_t MB = 1u << 20;
  bf16* q      = (bf16*)(ws + 0 * MB);    // live: qkv .. f1
  bf16* k      = (bf16*)(ws + 16 * MB);   // live: qkv .. f3
  bf16* v      = (bf16*)(ws + 32 * MB);   // live: qkv .. f1
  bf16* xn     = (bf16*)(ws + 48 * MB);   // dead after QKV
  bf16* a2_h   = (bf16*)(ws + 48 * MB);   // NS region overlays xn; dead after NS
  bf16* xz_h   = (bf16*)(ws + 52 * MB);
  bf16* t_h    = (bf16*)(ws + 56 * MB);
  bf16* u_h    = (bf16*)(ws + 60 * MB);
  float* Opart = (float*)(ws + 48 * MB);  // 16 MB, post-NS overlay
  float* lpart = (float*)(ws + 64 * MB);  // 1 MB
  bf16* zh0    = (bf16*)(ws + 65 * MB);   // NS scratch
  bf16* zh1    = (bf16*)(ws + 69 * MB);   // z0 + final a2inv (live to W gemm)
  bf16* xattn  = (bf16*)(ws + 73 * MB);   // 16 MB, written by f1
  bf16* wqkvT  = (bf16*)(ws + 73 * MB);   // 1.5 MB, overlays xattn (dead before f1)
  bf16* ql     = (bf16*)(ws + 89 * MB);
  bf16* kl     = (bf16*)(ws + 90 * MB);
  bf16* a3v    = (bf16*)(ws + 91 * MB);
  bf16* W      = (bf16*)(ws + 92 * MB);
  bf16* WT     = (bf16*)(ws + 93 * MB);
  bf16* woutT  = (bf16*)(ws + 94 * MB);   // 0.5 MB, live till outproj
  float* scal  = (float*)(ws + 94 * MB + 512 * 1024);
  bf16* zh[2] = {zh1, zh0};               // zh[0]=init z0; final back in zh1 after 6 iters

  // 0. merged weight cast+transpose (1 dispatch)
  prep_w<<<512, 256, 0, stream>>>(w_qkv, w_out, wqkvT, woutT);

  // 1. LayerNorm
  ln_kernel<<<16384, 64, 0, stream>>>(x, ln_w, ln_b, xn);

  // 2. QKV projection via BT=true (conflict-free staging), scatter into [b,h,n,d]
  gemm_k<128, 128, true, MODE_QKV><<<dim3(128, 12, 1), 256, 0, stream>>>(
      xn, wqkvT, nullptr, 16384, 1536, 512, 0, 0, 0, 1.f, 0.f, nullptr, nullptr, q, k, v);

  // 3. landmark means
  lm_kernel<<<dim3(32, 64), 256, 0, stream>>>(q, k, ql, kl);

  // 4. a2 = softmax(ql @ kl^T)
  gemm_k<64, 64, true, MODE_BF16><<<dim3(4, 4, 32), 256, 0, stream>>>(
      ql, kl, a2_h, 256, 256, 64, 16384, 16384, 65536, 1.f, 0.f, nullptr, nullptr, nullptr, nullptr, nullptr);
  softmax256<<<8192, 256, 0, stream>>>(a2_h);

  // 5. z0 = a2^T / (1 * max colsum)   (softmax row sums are exactly 1)
  init_scal<<<1, 1, 0, stream>>>(scal);
  red_col<<<dim3(32, 4), 64, 0, stream>>>(a2_h, scal);
  z0_k<<<dim3(32, 256), 256, 0, stream>>>(a2_h, scal, zh[0]);

  // 6. Newton-Schulz x6, diag-epilogues fused into the GEMMs
  int cur = 0;
  for (int it = 0; it < 6; it++) {
    gemm_k<64, 64, false, MODE_XZ><<<dim3(4, 4, 32), 256, 0, stream>>>(
        a2_h, zh[cur], nullptr, 256, 256, 256, 65536, 65536, 65536, 1.f, 7.f, nullptr, nullptr, xz_h, t_h, nullptr);
    gemm_k<64, 64, false, MODE_DIAG><<<dim3(4, 4, 32), 256, 0, stream>>>(
        xz_h, t_h, u_h, 256, 256, 256, 65536, 65536, 65536, 1.f, 15.f, nullptr, nullptr, nullptr, nullptr, nullptr);
    gemm_k<64, 64, false, MODE_DIAG><<<dim3(4, 4, 32), 256, 0, stream>>>(
        xz_h, u_h, t_h, 256, 256, 256, 65536, 65536, 65536, 1.f, 13.f, nullptr, nullptr, nullptr, nullptr, nullptr);
    gemm_k<64, 64, false, MODE_BF16><<<dim3(4, 4, 32), 256, 0, stream>>>(
        zh[cur], t_h, zh[1 - cur], 256, 256, 256, 65536, 65536, 65536, 0.25f, 0.f, nullptr, nullptr, nullptr, nullptr, nullptr);
    cur ^= 1;
  }
  // cur == 0: final pinv in zh[0] == zh1

  // 7. fused a3-softmax @ v (n-split partials + combine)
  f3_partial<<<dim3(2, 8, 32), 256, 0, stream>>>(ql, k, v, Opart, lpart);
  f3_combine<<<2048, 256, 0, stream>>>(Opart, lpart, a3v);

  // 8. W = a2inv @ a3v ; transpose for f1
  gemm_k<64, 64, false, MODE_BF16><<<dim3(4, 1, 32), 256, 0, stream>>>(
      zh[cur], a3v, W, 256, 64, 256, 65536, 16384, 16384, 1.f, 0.f, nullptr, nullptr, nullptr, nullptr, nullptr);
  wt_k<<<32, 256, 0, stream>>>(W, WT);

  // 9. fused a1-softmax @ W + Toeplitz conv + reorder -> xattn
  f1_attn<<<dim3(64, 32), 256, 0, stream>>>(q, kl, WT, v, w_conv, xattn);

  // 10. out = x + xattn @ w_out + b_out (fp32), BT=true conflict-free
  gemm_k<128, 128, true, MODE_RESID><<<dim3(128, 4, 1), 256, 0, stream>>>(
      xattn, woutT, out, 16384, 512, 512, 0, 0, 0, 1.f, 0.f, x, b_out, nullptr, nullptr, nullptr);
}